// Round 15
// baseline (396.795 us; speedup 1.0000x reference)
//
#include <hip/hip_runtime.h>
#include <math.h>

#define N_NODES 50000
#define N_EDGES 400000
#define H_HEADS 8
#define D_HEAD 16
#define R_TYPES 6
#define T_TYPES 4
#define DIM 128
#define BN 16                                      // nodes per GEMM tile
#define MAX_TILES ((N_NODES + BN - 1) / BN + T_TYPES)
#define NKEYS (N_NODES * R_TYPES)                  // 300000 (r,src) buckets, r-major
#define NBLK_K ((NKEYS + 255) / 256)               // 1172
#define NBLK_N ((N_NODES + 255) / 256)             // 196
#define EPAD_MAX (N_EDGES + R_TYPES * 32)          // padded edge-list bound
#define SM_SHIFT 8.0f                              // constant softmax shift

typedef unsigned short bf16_t;

__device__ __forceinline__ float bf2f(bf16_t u) {
    unsigned int v = ((unsigned int)u) << 16;
    return __int_as_float((int)v);
}
__device__ __forceinline__ bf16_t f2bf(float f) {
    unsigned int u = (unsigned int)__float_as_int(f);
    unsigned int lsb = (u >> 16) & 1u;
    u += 0x7fffu + lsb;                            // round-to-nearest-even
    return (bf16_t)(u >> 16);
}
__device__ __forceinline__ void bf2x(unsigned int u, float& a, float& b) {
    a = bf2f((bf16_t)(u & 0xffffu));
    b = bf2f((bf16_t)(u >> 16));
}
__device__ __forceinline__ unsigned int pk(float a, float b) {
    return (unsigned int)f2bf(a) | ((unsigned int)f2bf(b) << 16);
}

// ======================= generic scan pieces =======================

__global__ void k_scanA(const int* __restrict__ cnt, int* __restrict__ offs,
                        int* __restrict__ partial, int n) {
    __shared__ int tmp[256];
    int tid = threadIdx.x;
    int i = blockIdx.x * 256 + tid;
    int v = (i < n) ? cnt[i] : 0;
    tmp[tid] = v;
    __syncthreads();
    for (int o = 1; o < 256; o <<= 1) {
        int t = (tid >= o) ? tmp[tid - o] : 0;
        __syncthreads();
        tmp[tid] += t;
        __syncthreads();
    }
    if (i < n) offs[i] = tmp[tid] - v;           // exclusive within block
    if (tid == 255) partial[blockIdx.x] = tmp[255];
}

__global__ void k_rscan(int* __restrict__ a, int total) {
    __shared__ int tmp[256];
    __shared__ int carry_s;
    int tid = threadIdx.x;
    if (tid == 0) carry_s = 0;
    __syncthreads();
    for (int base = 0; base < total; base += 256) {
        int i = base + tid;
        int v = (i < total) ? a[i] : 0;
        tmp[tid] = v;
        __syncthreads();
        for (int o = 1; o < 256; o <<= 1) {
            int t = (tid >= o) ? tmp[tid - o] : 0;
            __syncthreads();
            tmp[tid] += t;
            __syncthreads();
        }
        int carry = carry_s;
        if (i < total) a[i] = carry + tmp[tid] - v;   // exclusive
        __syncthreads();
        if (tid == 255) carry_s = carry + tmp[255];
        __syncthreads();
    }
}

__global__ void k_scanC(int* __restrict__ offs, const int* __restrict__ partial, int n) {
    int i = blockIdx.x * 256 + threadIdx.x;
    if (i < n) offs[i] += partial[blockIdx.x];
}

__global__ void k_scanC2(int* __restrict__ offs, const int* __restrict__ partial,
                         int* __restrict__ cursor, int n) {
    int i = blockIdx.x * 256 + threadIdx.x;
    if (i < n) {
        int v = offs[i] + partial[blockIdx.x];
        offs[i] = v;
        cursor[i] = v;
    }
}

// ======================= r-major (r,SRC)-keyed CSR build, 32-padded r-segments =

__global__ void k_count6(const int* __restrict__ srcA, const int* __restrict__ etype,
                         int* __restrict__ deg6, int n) {
    int e = blockIdx.x * blockDim.x + threadIdx.x;
    if (e < n) atomicAdd(&deg6[etype[e] * N_NODES + srcA[e]], 1);
}

__global__ void k_countD(const int* __restrict__ dst, int* __restrict__ degD, int n) {
    int e = blockIdx.x * blockDim.x + threadIdx.x;
    if (e < n) atomicAdd(&degD[dst[e]], 1);
}

// padded per-r segment bases (each r-segment start aligned to 32)
__global__ void k_padsetup(const int* __restrict__ beg6, int* __restrict__ rb_pad,
                           int* __restrict__ rstart, int nE) {
    if (threadIdx.x == 0 && blockIdx.x == 0) {
        int o = 0;
        for (int r = 0; r < R_TYPES; ++r) {
            int st = beg6[r * N_NODES];
            rstart[r] = st;
            int en = (r < R_TYPES - 1) ? beg6[(r + 1) * N_NODES] : nE;
            rb_pad[r] = o;
            o += (en - st + 31) & ~31;
        }
        rb_pad[R_TYPES] = o;   // nEpad
    }
}

__global__ void k_cursor_pad(const int* __restrict__ beg6, const int* __restrict__ rb_pad,
                             const int* __restrict__ rstart, int* __restrict__ cursor6, int n) {
    int i = blockIdx.x * 256 + threadIdx.x;
    if (i < n) {
        int r = i / N_NODES;
        cursor6[i] = rb_pad[r] + (beg6[i] - rstart[r]);
    }
}

__global__ void k_scatter6(const int* __restrict__ src, const int* __restrict__ dst,
                           const int* __restrict__ etype, int* __restrict__ cursor6,
                           int* __restrict__ esrc_s, int* __restrict__ edst_s, int n) {
    int e = blockIdx.x * blockDim.x + threadIdx.x;
    if (e < n) {
        int key = etype[e] * N_NODES + src[e];
        int pos = atomicAdd(&cursor6[key], 1);
        esrc_s[pos] = src[e];
        edst_s[pos] = dst[e];
    }
}

// per-CSR-position dst-major write slot (skips padding sentinels)
__global__ void k_dpos(const int* __restrict__ edst_s, int* __restrict__ cursorD,
                       int* __restrict__ dpos, int n) {
    int p = blockIdx.x * blockDim.x + threadIdx.x;
    if (p < n) {
        int dn = edst_s[p];
        if (dn >= 0) dpos[p] = atomicAdd(&cursorD[dn], 1);
    }
}

// ======================= node type bucketing (padded 16-node tiles) ===========

__global__ void k_tcount_agg(const int* __restrict__ ntype, int* __restrict__ tcnt,
                             int* __restrict__ wpos, int n) {
    __shared__ int hist[T_TYPES];
    __shared__ int base[T_TYPES];
    int tid = threadIdx.x;
    if (tid < T_TYPES) hist[tid] = 0;
    __syncthreads();
    int i = blockIdx.x * 256 + tid;
    int t = 0, rank = 0;
    if (i < n) {
        t = ntype[i];
        rank = atomicAdd(&hist[t], 1);
    }
    __syncthreads();
    if (tid < T_TYPES)
        base[tid] = (hist[tid] > 0) ? atomicAdd(&tcnt[tid], hist[tid]) : 0;
    __syncthreads();
    if (i < n) wpos[i] = base[t] + rank;
}

__global__ void k_tsetup(const int* __restrict__ tcnt, int* __restrict__ pbase,
                         int* __restrict__ ntiles_g, int* __restrict__ tile_type) {
    __shared__ int off[T_TYPES + 1];
    if (threadIdx.x == 0) {
        int o = 0;
        for (int t = 0; t < T_TYPES; ++t) {
            off[t] = o;
            pbase[t] = o * BN;
            o += (tcnt[t] + BN - 1) / BN;
        }
        off[T_TYPES] = o;
        *ntiles_g = o;
    }
    __syncthreads();
    int total = off[T_TYPES];
    for (int i = threadIdx.x; i < total; i += blockDim.x) {
        int t = 0;
        while (t < T_TYPES - 1 && i >= off[t + 1]) ++t;
        tile_type[i] = t;
    }
}

__global__ void k_tscatter2(const int* __restrict__ ntype, const int* __restrict__ wpos,
                            const int* __restrict__ pbase, int* __restrict__ nlist, int n) {
    int i = blockIdx.x * 256 + threadIdx.x;
    if (i < n) nlist[pbase[ntype[i]] + wpos[i]] = i;
}

// ======================= K1: tiled typed-linear k,q,v (bf16 out) ==========

__global__ __launch_bounds__(192) void k_kqv_gemm4(
    const float* __restrict__ x, const int* __restrict__ nlist,
    const int* __restrict__ tile_type, const int* __restrict__ ntiles_g,
    const float* __restrict__ Wk, const float* __restrict__ Wq,
    const float* __restrict__ Wv,
    bf16_t* __restrict__ kb, bf16_t* __restrict__ qb, bf16_t* __restrict__ vb) {
    __shared__ float xs[BN][DIM];   // 8 KB
    __shared__ int sids[BN];
    int b = blockIdx.x;
    if (b >= *ntiles_g) return;
    int tid = threadIdx.x;
    if (tid < BN) sids[tid] = nlist[b * BN + tid];
    __syncthreads();
    for (int idx = tid; idx < BN * (DIM / 4); idx += 192) {
        int row = idx >> 5;
        int q4 = idx & 31;
        int nid = sids[row];
        float4 v4 = make_float4(0.f, 0.f, 0.f, 0.f);
        if (nid >= 0) v4 = *(const float4*)(x + (size_t)nid * DIM + q4 * 4);
        *(float4*)(&xs[row][q4 * 4]) = v4;
    }
    __syncthreads();
    int lt = tid / 96;
    int wi = tid % 96;
    int mat = wi >> 5;
    int colq = wi & 31;
    int t = tile_type[b];
    const float* W = (mat == 0 ? Wk : (mat == 1 ? Wq : Wv))
                     + (size_t)t * DIM * DIM + colq * 4;
    float acc[8][4];
#pragma unroll
    for (int n = 0; n < 8; ++n) {
        acc[n][0] = 0.f; acc[n][1] = 0.f; acc[n][2] = 0.f; acc[n][3] = 0.f;
    }
    const float* xbase = &xs[lt * 8][0];
    for (int dq = 0; dq < 32; ++dq) {
        float4 w0 = *(const float4*)(W + (size_t)(dq * 4 + 0) * DIM);
        float4 w1 = *(const float4*)(W + (size_t)(dq * 4 + 1) * DIM);
        float4 w2 = *(const float4*)(W + (size_t)(dq * 4 + 2) * DIM);
        float4 w3 = *(const float4*)(W + (size_t)(dq * 4 + 3) * DIM);
#pragma unroll
        for (int n = 0; n < 8; ++n) {
            float4 xv = *(const float4*)(xbase + n * DIM + dq * 4);
            acc[n][0] = fmaf(xv.x, w0.x, acc[n][0]);
            acc[n][0] = fmaf(xv.y, w1.x, acc[n][0]);
            acc[n][0] = fmaf(xv.z, w2.x, acc[n][0]);
            acc[n][0] = fmaf(xv.w, w3.x, acc[n][0]);
            acc[n][1] = fmaf(xv.x, w0.y, acc[n][1]);
            acc[n][1] = fmaf(xv.y, w1.y, acc[n][1]);
            acc[n][1] = fmaf(xv.z, w2.y, acc[n][1]);
            acc[n][1] = fmaf(xv.w, w3.y, acc[n][1]);
            acc[n][2] = fmaf(xv.x, w0.z, acc[n][2]);
            acc[n][2] = fmaf(xv.y, w1.z, acc[n][2]);
            acc[n][2] = fmaf(xv.z, w2.z, acc[n][2]);
            acc[n][2] = fmaf(xv.w, w3.z, acc[n][2]);
            acc[n][3] = fmaf(xv.x, w0.w, acc[n][3]);
            acc[n][3] = fmaf(xv.y, w1.w, acc[n][3]);
            acc[n][3] = fmaf(xv.z, w2.w, acc[n][3]);
            acc[n][3] = fmaf(xv.w, w3.w, acc[n][3]);
        }
    }
    bf16_t* ob = (mat == 0 ? kb : (mat == 1 ? qb : vb));
#pragma unroll
    for (int n = 0; n < 8; ++n) {
        int nid = sids[lt * 8 + n];
        if (nid >= 0) {
            ushort4 o4;
            o4.x = f2bf(acc[n][0]); o4.y = f2bf(acc[n][1]);
            o4.z = f2bf(acc[n][2]); o4.w = f2bf(acc[n][3]);
            *(ushort4*)(ob + (size_t)nid * DIM + colq * 4) = o4;
        }
    }
}

// ======================= K2: fused edge kernel (r-uniform blocks) =============
// r-segments padded to 32 -> every block has ONE r: single A/M LDS slot
// (16.9 KB, 2x occupancy vs 2-slot). Dummy entries (esrc=-1) skipped.

__global__ __launch_bounds__(256) void k_edge_m2(
    const bf16_t* __restrict__ kbuf, const bf16_t* __restrict__ qbuf,
    const bf16_t* __restrict__ vbuf,
    const int* __restrict__ esrc_s, const int* __restrict__ edst_s,
    const int* __restrict__ rb_pad, const int* __restrict__ dpos,
    const float* __restrict__ rel_att, const float* __restrict__ rel_msg,
    const float* __restrict__ rel_pri,
    float* __restrict__ ex_out, bf16_t* __restrict__ m_out) {
    __shared__ float A2[8 * 260];   // 8.3 KB
    __shared__ float M2[8 * 260];   // 8.3 KB
    __shared__ float pri[8];
    __shared__ int r_s;
    int b = blockIdx.x;
    int e0 = b * 32;
    int tid = threadIdx.x;
    if (tid == 0) {
        int r = 0;
#pragma unroll
        for (int q = 1; q < R_TYPES; ++q) if (e0 >= rb_pad[q]) r = q;
        r_s = r;
    }
    __syncthreads();
    int r = r_s;
    for (int idx = tid; idx < 2048; idx += 256) {
        int h = idx >> 8, dj = idx & 255;
        A2[h * 260 + dj] = rel_att[(h * R_TYPES + r) * 256 + dj];
        M2[h * 260 + dj] = rel_msg[(h * R_TYPES + r) * 256 + dj];
    }
    if (tid < 8) pri[tid] = rel_pri[tid * R_TYPES + r] * 0.25f;
    __syncthreads();
    int el = tid >> 3;
    int h  = tid & 7;
    int q2 = e0 + el;
    int s = esrc_s[q2];
    if (s < 0) return;                       // padding sentinel
    int dn = edst_s[q2];
    const uint4* kp = (const uint4*)(kbuf + (size_t)s  * DIM + h * 16);
    const uint4* qp = (const uint4*)(qbuf + (size_t)dn * DIM + h * 16);
    const uint4* vp = (const uint4*)(vbuf + (size_t)s  * DIM + h * 16);
    uint4 ka = kp[0], kb4 = kp[1];
    uint4 qa = qp[0], qb4 = qp[1];
    uint4 va = vp[0], vb4 = vp[1];
    float kk[16], qq[16], vv[16];
    bf2x(ka.x,  kk[0],  kk[1]);  bf2x(ka.y,  kk[2],  kk[3]);
    bf2x(ka.z,  kk[4],  kk[5]);  bf2x(ka.w,  kk[6],  kk[7]);
    bf2x(kb4.x, kk[8],  kk[9]);  bf2x(kb4.y, kk[10], kk[11]);
    bf2x(kb4.z, kk[12], kk[13]); bf2x(kb4.w, kk[14], kk[15]);
    bf2x(qa.x,  qq[0],  qq[1]);  bf2x(qa.y,  qq[2],  qq[3]);
    bf2x(qa.z,  qq[4],  qq[5]);  bf2x(qa.w,  qq[6],  qq[7]);
    bf2x(qb4.x, qq[8],  qq[9]);  bf2x(qb4.y, qq[10], qq[11]);
    bf2x(qb4.z, qq[12], qq[13]); bf2x(qb4.w, qq[14], qq[15]);
    bf2x(va.x,  vv[0],  vv[1]);  bf2x(va.y,  vv[2],  vv[3]);
    bf2x(va.z,  vv[4],  vv[5]);  bf2x(va.w,  vv[6],  vv[7]);
    bf2x(vb4.x, vv[8],  vv[9]);  bf2x(vb4.y, vv[10], vv[11]);
    bf2x(vb4.z, vv[12], vv[13]); bf2x(vb4.w, vv[14], vv[15]);

    // QK^T: accj[j] = sum_d k_d A[d][j];  a = sum_j accj[j] q_j
    const float4* A4 = (const float4*)&A2[h * 260];
    float accj[16];
#pragma unroll
    for (int j = 0; j < 16; ++j) accj[j] = 0.f;
#pragma unroll
    for (int d = 0; d < 16; ++d) {
        float kd = kk[d];
#pragma unroll
        for (int jj = 0; jj < 4; ++jj) {
            float4 a4 = A4[d * 4 + jj];
            accj[jj * 4 + 0] = fmaf(kd, a4.x, accj[jj * 4 + 0]);
            accj[jj * 4 + 1] = fmaf(kd, a4.y, accj[jj * 4 + 1]);
            accj[jj * 4 + 2] = fmaf(kd, a4.z, accj[jj * 4 + 2]);
            accj[jj * 4 + 3] = fmaf(kd, a4.w, accj[jj * 4 + 3]);
        }
    }
    float a = 0.f;
#pragma unroll
    for (int j = 0; j < 16; ++j) a = fmaf(accj[j], qq[j], a);
    float ex = __expf(a * pri[h] - SM_SHIFT);

    // message: m[j] = ex * sum_d v_d M[d][j]
    const float4* M4 = (const float4*)&M2[h * 260];
    float mj[16];
#pragma unroll
    for (int j = 0; j < 16; ++j) mj[j] = 0.f;
#pragma unroll
    for (int d = 0; d < 16; ++d) {
        float vd = vv[d];
#pragma unroll
        for (int jj = 0; jj < 4; ++jj) {
            float4 m4 = M4[d * 4 + jj];
            mj[jj * 4 + 0] = fmaf(vd, m4.x, mj[jj * 4 + 0]);
            mj[jj * 4 + 1] = fmaf(vd, m4.y, mj[jj * 4 + 1]);
            mj[jj * 4 + 2] = fmaf(vd, m4.z, mj[jj * 4 + 2]);
            mj[jj * 4 + 3] = fmaf(vd, m4.w, mj[jj * 4 + 3]);
        }
    }
    int dp = dpos[q2];
    ex_out[(size_t)dp * 8 + h] = ex;
    uint4 o0, o1;
    o0.x = pk(ex * mj[0],  ex * mj[1]);  o0.y = pk(ex * mj[2],  ex * mj[3]);
    o0.z = pk(ex * mj[4],  ex * mj[5]);  o0.w = pk(ex * mj[6],  ex * mj[7]);
    o1.x = pk(ex * mj[8],  ex * mj[9]);  o1.y = pk(ex * mj[10], ex * mj[11]);
    o1.z = pk(ex * mj[12], ex * mj[13]); o1.w = pk(ex * mj[14], ex * mj[15]);
    uint4* op = (uint4*)(m_out + (size_t)dp * DIM + h * 16);
    op[0] = o0; op[1] = o1;
}

// ======================= K3: streaming aggregate ==============================

__global__ __launch_bounds__(256) void k_agg_stream(
    const bf16_t* __restrict__ m_out, const float* __restrict__ ex_out,
    const int* __restrict__ doffD, const int* __restrict__ degD,
    float* __restrict__ hacc, int n) {
    int tid = threadIdx.x;
    int nb = tid >> 7;
    int lane2 = tid & 127;
    int node = blockIdx.x * 2 + nb;
    if (node >= n) return;
    int h = lane2 >> 4;
    int off = doffD[node];
    int dg  = degD[node];
    float acc = 0.f, den = 0.f;
#pragma unroll 4
    for (int j = 0; j < dg; ++j) {
        den += ex_out[(size_t)(off + j) * 8 + h];                 // broadcast
        acc += bf2f(m_out[(size_t)(off + j) * DIM + lane2]);      // coalesced row
    }
    hacc[(size_t)node * DIM + lane2] = acc / fmaxf(den, 1e-9f);
}

// ======================= K4: tiled Wa + gate + residual + LayerNorm ===========

__global__ __launch_bounds__(256) void k_final_gemm(
    const float* __restrict__ x, const int* __restrict__ nlist,
    const int* __restrict__ tile_type, const int* __restrict__ ntiles_g,
    const float* __restrict__ Wa, const float* __restrict__ skip,
    const float* __restrict__ gamma, const float* __restrict__ beta,
    float* __restrict__ out) {
    __shared__ float hs[BN][DIM];
    __shared__ float ys[BN][DIM];
    __shared__ int sids[BN];
    __shared__ float mred[BN], ired[BN];
    int b = blockIdx.x;
    if (b >= *ntiles_g) return;
    int tid = threadIdx.x;
    if (tid < BN) sids[tid] = nlist[b * BN + tid];
    __syncthreads();
    for (int idx = tid; idx < BN * DIM; idx += 256) {
        int row = idx >> 7, col = idx & 127;
        int nid = sids[row];
        hs[row][col] = (nid >= 0) ? out[(size_t)nid * DIM + col] : 0.f;
    }
    __syncthreads();
    int t = tile_type[b];
    int half = tid >> 7, col = tid & 127;
    const float* W = Wa + (size_t)t * DIM * DIM;
    float acc[8];
#pragma unroll
    for (int n = 0; n < 8; ++n) acc[n] = 0.f;
#pragma unroll 4
    for (int d = 0; d < DIM; ++d) {
        float w = W[d * DIM + col];
#pragma unroll
        for (int n = 0; n < 8; ++n) acc[n] = fmaf(hs[half * 8 + n][d], w, acc[n]);
    }
    float gte = 1.f / (1.f + __expf(-skip[t]));
#pragma unroll
    for (int n = 0; n < 8; ++n) {
        int row = half * 8 + n;
        int nid = sids[row];
        float xv = (nid >= 0) ? x[(size_t)nid * DIM + col] : 0.f;
        ys[row][col] = xv * (2.f - gte) + acc[n] * gte;
    }
    __syncthreads();
    int ng = tid >> 4, l16 = tid & 15;
    float s = 0.f, s2 = 0.f;
#pragma unroll
    for (int k2 = 0; k2 < 8; ++k2) {
        float yv = ys[ng][l16 + 16 * k2];
        s += yv; s2 += yv * yv;
    }
#pragma unroll
    for (int m = 1; m < 16; m <<= 1) {
        s  += __shfl_xor(s, m, 64);
        s2 += __shfl_xor(s2, m, 64);
    }
    if (l16 == 0) {
        float mu = s * (1.f / DIM);
        float var = s2 * (1.f / DIM) - mu * mu;
        mred[ng] = mu;
        ired[ng] = rsqrtf(var + 1e-5f);
    }
    __syncthreads();
    float gm = gamma[col], bt = beta[col];
#pragma unroll
    for (int n = 0; n < 8; ++n) {
        int row = half * 8 + n;
        int nid = sids[row];
        if (nid >= 0)
            out[(size_t)nid * DIM + col] = (ys[row][col] - mred[row]) * ired[row] * gm + bt;
    }
}

// ======================= launcher =======================

extern "C" void kernel_launch(void* const* d_in, const int* in_sizes, int n_in,
                              void* d_out, int out_size, void* d_ws, size_t ws_size,
                              hipStream_t stream) {
    const float* x       = (const float*)d_in[0];
    const int*   src     = (const int*)d_in[1];
    const int*   dst     = (const int*)d_in[2];
    const int*   ntype   = (const int*)d_in[3];
    const int*   etype   = (const int*)d_in[4];
    const float* Wk      = (const float*)d_in[5];
    const float* Wq      = (const float*)d_in[6];
    const float* Wv      = (const float*)d_in[7];
    const float* Wa      = (const float*)d_in[8];
    const float* rel_pri = (const float*)d_in[9];
    const float* rel_att = (const float*)d_in[10];
    const float* rel_msg = (const float*)d_in[11];
    const float* skip    = (const float*)d_in[12];
    const float* gamma   = (const float*)d_in[13];
    const float* beta    = (const float*)d_in[14];
    float* out = (float*)d_out;

    const int N = N_NODES, E = N_EDGES;

    // workspace layout
    char* ws = (char*)d_ws;
    float* ex_out = (float*)ws;                         // E*8 f32 (12.8 MB)
    int* deg6    = (int*)(ex_out + (size_t)E * H_HEADS);// NKEYS
    int* beg6    = deg6 + NKEYS;                        // NKEYS
    int* cursor6 = beg6 + NKEYS;                        // NKEYS
    int* partial6 = cursor6 + NKEYS;                    // NBLK_K
    int* degD    = partial6 + NBLK_K;                   // N
    int* doffD   = degD + N;                            // N
    int* cursorD = doffD + N;                           // N
    int* partialD = cursorD + N;                        // NBLK_N
    int* rb_pad  = partialD + NBLK_N;                   // R_TYPES+1
    int* rstart  = rb_pad + R_TYPES + 1;                // R_TYPES
    int* dpos    = rstart + R_TYPES;                    // EPAD_MAX
    int* esrc_s  = dpos + EPAD_MAX;                     // EPAD_MAX
    int* edst_s  = esrc_s + EPAD_MAX;                   // EPAD_MAX
    int* tcnt    = edst_s + EPAD_MAX;                   // 4
    int* pbase   = tcnt + T_TYPES;                      // 4
    int* ntiles  = pbase + T_TYPES;                     // 1
    int* tile_type = ntiles + 1;                        // MAX_TILES
    int* nlist   = tile_type + MAX_TILES;               // MAX_TILES*BN
    int* wpos    = nlist + (size_t)MAX_TILES * BN;      // N
    bf16_t* kb   = (bf16_t*)(wpos + N);                 // N*DIM bf16
    bf16_t* qb   = kb + (size_t)N * DIM;                // N*DIM
    bf16_t* vb   = qb + (size_t)N * DIM;                // N*DIM
    bf16_t* m_out = vb + (size_t)N * DIM;               // E*DIM bf16 (102.4 MB)

    const int nbE = (E + 255) / 256;
    const int nbEP = (EPAD_MAX + 255) / 256;

    // r-major (r,src)-keyed CSR build (32-padded r-segments) + dst-major offsets
    hipMemsetAsync(deg6, 0, (size_t)NKEYS * sizeof(int), stream);
    hipMemsetAsync(degD, 0, (size_t)N * sizeof(int), stream);
    hipMemsetAsync(esrc_s, 0xFF, (size_t)EPAD_MAX * sizeof(int), stream);
    hipMemsetAsync(edst_s, 0xFF, (size_t)EPAD_MAX * sizeof(int), stream);
    k_count6<<<nbE, 256, 0, stream>>>(src, etype, deg6, E);
    k_countD<<<nbE, 256, 0, stream>>>(dst, degD, E);
    k_scanA<<<NBLK_K, 256, 0, stream>>>(deg6, beg6, partial6, NKEYS);
    k_rscan<<<1, 256, 0, stream>>>(partial6, NBLK_K);
    k_scanC<<<NBLK_K, 256, 0, stream>>>(beg6, partial6, NKEYS);
    k_padsetup<<<1, 64, 0, stream>>>(beg6, rb_pad, rstart, E);
    k_cursor_pad<<<NBLK_K, 256, 0, stream>>>(beg6, rb_pad, rstart, cursor6, NKEYS);
    k_scanA<<<NBLK_N, 256, 0, stream>>>(degD, doffD, partialD, N);
    k_rscan<<<1, 256, 0, stream>>>(partialD, NBLK_N);
    k_scanC2<<<NBLK_N, 256, 0, stream>>>(doffD, partialD, cursorD, N);
    k_scatter6<<<nbE, 256, 0, stream>>>(
        src, dst, etype, cursor6, esrc_s, edst_s, E);
    k_dpos<<<nbEP, 256, 0, stream>>>(edst_s, cursorD, dpos, EPAD_MAX);

    // node type buckets (padded 16-node tiles)
    hipMemsetAsync(tcnt, 0, T_TYPES * sizeof(int), stream);
    k_tcount_agg<<<NBLK_N, 256, 0, stream>>>(ntype, tcnt, wpos, N);
    k_tsetup<<<1, 256, 0, stream>>>(tcnt, pbase, ntiles, tile_type);
    hipMemsetAsync(nlist, 0xFF, (size_t)MAX_TILES * BN * sizeof(int), stream);
    k_tscatter2<<<NBLK_N, 256, 0, stream>>>(ntype, wpos, pbase, nlist, N);

    // projections (tiled per-type GEMM, bf16 outputs)
    k_kqv_gemm4<<<MAX_TILES, 192, 0, stream>>>(
        x, nlist, tile_type, ntiles, Wk, Wq, Wv, kb, qb, vb);

    // fused edge kernel: QK^T, exp, M.v -> dst-major ex/m (r-uniform blocks)
    k_edge_m2<<<EPAD_MAX / 32, 256, 0, stream>>>(
        kb, qb, vb, esrc_s, edst_s, rb_pad, dpos,
        rel_att, rel_msg, rel_pri, ex_out, m_out);

    // streaming per-node aggregate -> d_out (scratch)
    k_agg_stream<<<(N + 1) / 2, 256, 0, stream>>>(
        m_out, ex_out, doffD, degD, out, N);

    // output projection + gate + residual + LayerNorm (in place on d_out)
    k_final_gemm<<<MAX_TILES, 256, 0, stream>>>(
        x, nlist, tile_type, ntiles, Wa, skip, gamma, beta, out);
}

// Round 17
// 371.600 us; speedup vs baseline: 1.0678x; 1.0678x over previous
//
#include <hip/hip_runtime.h>
#include <math.h>

#define N_NODES 50000
#define N_EDGES 400000
#define H_HEADS 8
#define D_HEAD 16
#define R_TYPES 6
#define T_TYPES 4
#define DIM 128
#define BN 16                                      // nodes per GEMM tile
#define MAX_TILES ((N_NODES + BN - 1) / BN + T_TYPES)
#define NKEYS (N_NODES * R_TYPES)                  // 300000 (r,src) buckets, r-major
#define NBLK_K ((NKEYS + 255) / 256)               // 1172
#define NBLK_N ((N_NODES + 255) / 256)             // 196
#define EPAD_ALIGN 128                             // r-segment alignment (= edges/block)
#define EPAD_MAX (N_EDGES + R_TYPES * EPAD_ALIGN)  // 400768
#define SM_SHIFT 8.0f                              // constant softmax shift

typedef unsigned short bf16_t;

__device__ __forceinline__ float bf2f(bf16_t u) {
    unsigned int v = ((unsigned int)u) << 16;
    return __int_as_float((int)v);
}
__device__ __forceinline__ bf16_t f2bf(float f) {
    unsigned int u = (unsigned int)__float_as_int(f);
    unsigned int lsb = (u >> 16) & 1u;
    u += 0x7fffu + lsb;                            // round-to-nearest-even
    return (bf16_t)(u >> 16);
}
__device__ __forceinline__ void bf2x(unsigned int u, float& a, float& b) {
    a = bf2f((bf16_t)(u & 0xffffu));
    b = bf2f((bf16_t)(u >> 16));
}
__device__ __forceinline__ unsigned int pk(float a, float b) {
    return (unsigned int)f2bf(a) | ((unsigned int)f2bf(b) << 16);
}

// ======================= scan pieces =======================

__global__ void k_scanA(const int* __restrict__ cnt, int* __restrict__ offs,
                        int* __restrict__ partial, int n) {
    __shared__ int tmp[256];
    int tid = threadIdx.x;
    int i = blockIdx.x * 256 + tid;
    int v = (i < n) ? cnt[i] : 0;
    tmp[tid] = v;
    __syncthreads();
    for (int o = 1; o < 256; o <<= 1) {
        int t = (tid >= o) ? tmp[tid - o] : 0;
        __syncthreads();
        tmp[tid] += t;
        __syncthreads();
    }
    if (i < n) offs[i] = tmp[tid] - v;           // exclusive within block
    if (tid == 255) partial[blockIdx.x] = tmp[255];
}

__device__ void dev_rscan(int* a, int total, int* tmp, int* carry_s) {
    int tid = threadIdx.x;
    if (tid == 0) *carry_s = 0;
    __syncthreads();
    for (int base = 0; base < total; base += 256) {
        int i = base + tid;
        int v = (i < total) ? a[i] : 0;
        tmp[tid] = v;
        __syncthreads();
        for (int o = 1; o < 256; o <<= 1) {
            int t = (tid >= o) ? tmp[tid - o] : 0;
            __syncthreads();
            tmp[tid] += t;
            __syncthreads();
        }
        int carry = *carry_s;
        if (i < total) a[i] = carry + tmp[tid] - v;   // exclusive
        __syncthreads();
        if (tid == 255) *carry_s = carry + tmp[255];
        __syncthreads();
    }
}

__global__ void k_rscan2(int* __restrict__ a, int na, int* __restrict__ b, int nb) {
    __shared__ int tmp[256];
    __shared__ int carry_s;
    dev_rscan(a, na, tmp, &carry_s);
    __syncthreads();
    dev_rscan(b, nb, tmp, &carry_s);
}

__global__ void k_scanC2(int* __restrict__ offs, const int* __restrict__ partial,
                         int* __restrict__ cursor, int n) {
    int i = blockIdx.x * 256 + threadIdx.x;
    if (i < n) {
        int v = offs[i] + partial[blockIdx.x];
        offs[i] = v;
        cursor[i] = v;
    }
}

// ======================= counts (fused) =======================

__global__ void k_count_all(const int* __restrict__ src, const int* __restrict__ dst,
                            const int* __restrict__ etype,
                            int* __restrict__ deg6, int* __restrict__ degD, int n) {
    int e = blockIdx.x * blockDim.x + threadIdx.x;
    if (e < n) {
        atomicAdd(&deg6[etype[e] * N_NODES + src[e]], 1);
        atomicAdd(&degD[dst[e]], 1);
    }
}

__global__ void k_tcount_agg(const int* __restrict__ ntype, int* __restrict__ tcnt,
                             int* __restrict__ wpos, int n) {
    __shared__ int hist[T_TYPES];
    __shared__ int base[T_TYPES];
    int tid = threadIdx.x;
    if (tid < T_TYPES) hist[tid] = 0;
    __syncthreads();
    int i = blockIdx.x * 256 + tid;
    int t = 0, rank = 0;
    if (i < n) {
        t = ntype[i];
        rank = atomicAdd(&hist[t], 1);
    }
    __syncthreads();
    if (tid < T_TYPES)
        base[tid] = (hist[tid] > 0) ? atomicAdd(&tcnt[tid], hist[tid]) : 0;
    __syncthreads();
    if (i < n) wpos[i] = base[t] + rank;
}

// ======================= single-block serial setup (fused) ====================
// padded r-segment bases + esrc sentinels in pad gaps + type-tile setup +
// tile_type fill + nlist pad sentinels.

__global__ void k_small_setup(const int* __restrict__ offs6, const int* __restrict__ partial6,
                              const int* __restrict__ tcnt,
                              int* __restrict__ rb_pad, int* __restrict__ rstart,
                              int* __restrict__ pbase, int* __restrict__ ntiles_g,
                              int* __restrict__ tile_type, int* __restrict__ nlist,
                              int* __restrict__ esrc_s, int nE) {
    __shared__ int rbp[R_TYPES + 1], rst[R_TYPES], len[R_TYPES];
    __shared__ int off_t[T_TYPES + 1];
    int tid = threadIdx.x;
    if (tid == 0) {
        int o = 0;
        int st = offs6[0] + partial6[0];
        for (int r = 0; r < R_TYPES; ++r) {
            int idx1 = (r + 1) * N_NODES;
            int en = (r < R_TYPES - 1) ? (offs6[idx1] + partial6[idx1 >> 8]) : nE;
            rst[r] = st; rstart[r] = st;
            len[r] = en - st;
            rbp[r] = o; rb_pad[r] = o;
            o += (en - st + EPAD_ALIGN - 1) & ~(EPAD_ALIGN - 1);
            st = en;
        }
        rbp[R_TYPES] = o; rb_pad[R_TYPES] = o;
        int o2 = 0;
        for (int t = 0; t < T_TYPES; ++t) {
            off_t[t] = o2;
            pbase[t] = o2 * BN;
            o2 += (tcnt[t] + BN - 1) / BN;
        }
        off_t[T_TYPES] = o2;
        *ntiles_g = o2;
    }
    __syncthreads();
    // esrc sentinels: per-r pad gaps + tail beyond nEpad
    for (int r = 0; r < R_TYPES; ++r)
        for (int i = rbp[r] + len[r] + tid; i < rbp[r + 1]; i += 256) esrc_s[i] = -1;
    for (int i = rbp[R_TYPES] + tid; i < EPAD_MAX; i += 256) esrc_s[i] = -1;
    // tile_type fill
    int total = off_t[T_TYPES];
    for (int i = tid; i < total; i += 256) {
        int t = 0;
        while (t < T_TYPES - 1 && i >= off_t[t + 1]) ++t;
        tile_type[i] = t;
    }
    // nlist pad sentinels
    for (int t = 0; t < T_TYPES; ++t) {
        int b0 = off_t[t] * BN + tcnt[t];
        int b1 = off_t[t + 1] * BN;
        for (int i = b0 + tid; i < b1; i += 256) nlist[i] = -1;
    }
}

// cursor6 = padded scatter slot base per (r,src) key
__global__ void k_cursor_pad(const int* __restrict__ offs6, const int* __restrict__ partial6,
                             const int* __restrict__ rb_pad, const int* __restrict__ rstart,
                             int* __restrict__ cursor6, int n) {
    int i = blockIdx.x * 256 + threadIdx.x;
    if (i < n) {
        int r = i / N_NODES;
        int v = offs6[i] + partial6[i >> 8];
        cursor6[i] = rb_pad[r] + (v - rstart[r]);
    }
}

// scatter into padded (r,src)-CSR + assign dst-major write slot (fused)
__global__ void k_scatter6D(const int* __restrict__ src, const int* __restrict__ dst,
                            const int* __restrict__ etype, int* __restrict__ cursor6,
                            int* __restrict__ cursorD,
                            int* __restrict__ esrc_s, int* __restrict__ edst_s,
                            int* __restrict__ dpos, int n) {
    int e = blockIdx.x * blockDim.x + threadIdx.x;
    if (e < n) {
        int dn = dst[e];
        int key = etype[e] * N_NODES + src[e];
        int pos = atomicAdd(&cursor6[key], 1);
        esrc_s[pos] = src[e];
        edst_s[pos] = dn;
        dpos[pos] = atomicAdd(&cursorD[dn], 1);
    }
}

__global__ void k_tscatter2(const int* __restrict__ ntype, const int* __restrict__ wpos,
                            const int* __restrict__ pbase, int* __restrict__ nlist, int n) {
    int i = blockIdx.x * 256 + threadIdx.x;
    if (i < n) nlist[pbase[ntype[i]] + wpos[i]] = i;
}

// ======================= K1: tiled typed-linear k,q,v (bf16 out) ==========

__global__ __launch_bounds__(192) void k_kqv_gemm4(
    const float* __restrict__ x, const int* __restrict__ nlist,
    const int* __restrict__ tile_type, const int* __restrict__ ntiles_g,
    const float* __restrict__ Wk, const float* __restrict__ Wq,
    const float* __restrict__ Wv,
    bf16_t* __restrict__ kb, bf16_t* __restrict__ qb, bf16_t* __restrict__ vb) {
    __shared__ float xs[BN][DIM];   // 8 KB
    __shared__ int sids[BN];
    int b = blockIdx.x;
    if (b >= *ntiles_g) return;
    int tid = threadIdx.x;
    if (tid < BN) sids[tid] = nlist[b * BN + tid];
    __syncthreads();
    for (int idx = tid; idx < BN * (DIM / 4); idx += 192) {
        int row = idx >> 5;
        int q4 = idx & 31;
        int nid = sids[row];
        float4 v4 = make_float4(0.f, 0.f, 0.f, 0.f);
        if (nid >= 0) v4 = *(const float4*)(x + (size_t)nid * DIM + q4 * 4);
        *(float4*)(&xs[row][q4 * 4]) = v4;
    }
    __syncthreads();
    int lt = tid / 96;
    int wi = tid % 96;
    int mat = wi >> 5;
    int colq = wi & 31;
    int t = tile_type[b];
    const float* W = (mat == 0 ? Wk : (mat == 1 ? Wq : Wv))
                     + (size_t)t * DIM * DIM + colq * 4;
    float acc[8][4];
#pragma unroll
    for (int n = 0; n < 8; ++n) {
        acc[n][0] = 0.f; acc[n][1] = 0.f; acc[n][2] = 0.f; acc[n][3] = 0.f;
    }
    const float* xbase = &xs[lt * 8][0];
    for (int dq = 0; dq < 32; ++dq) {
        float4 w0 = *(const float4*)(W + (size_t)(dq * 4 + 0) * DIM);
        float4 w1 = *(const float4*)(W + (size_t)(dq * 4 + 1) * DIM);
        float4 w2 = *(const float4*)(W + (size_t)(dq * 4 + 2) * DIM);
        float4 w3 = *(const float4*)(W + (size_t)(dq * 4 + 3) * DIM);
#pragma unroll
        for (int n = 0; n < 8; ++n) {
            float4 xv = *(const float4*)(xbase + n * DIM + dq * 4);
            acc[n][0] = fmaf(xv.x, w0.x, acc[n][0]);
            acc[n][0] = fmaf(xv.y, w1.x, acc[n][0]);
            acc[n][0] = fmaf(xv.z, w2.x, acc[n][0]);
            acc[n][0] = fmaf(xv.w, w3.x, acc[n][0]);
            acc[n][1] = fmaf(xv.x, w0.y, acc[n][1]);
            acc[n][1] = fmaf(xv.y, w1.y, acc[n][1]);
            acc[n][1] = fmaf(xv.z, w2.y, acc[n][1]);
            acc[n][1] = fmaf(xv.w, w3.y, acc[n][1]);
            acc[n][2] = fmaf(xv.x, w0.z, acc[n][2]);
            acc[n][2] = fmaf(xv.y, w1.z, acc[n][2]);
            acc[n][2] = fmaf(xv.z, w2.z, acc[n][2]);
            acc[n][2] = fmaf(xv.w, w3.z, acc[n][2]);
            acc[n][3] = fmaf(xv.x, w0.w, acc[n][3]);
            acc[n][3] = fmaf(xv.y, w1.w, acc[n][3]);
            acc[n][3] = fmaf(xv.z, w2.w, acc[n][3]);
            acc[n][3] = fmaf(xv.w, w3.w, acc[n][3]);
        }
    }
    bf16_t* ob = (mat == 0 ? kb : (mat == 1 ? qb : vb));
#pragma unroll
    for (int n = 0; n < 8; ++n) {
        int nid = sids[lt * 8 + n];
        if (nid >= 0) {
            ushort4 o4;
            o4.x = f2bf(acc[n][0]); o4.y = f2bf(acc[n][1]);
            o4.z = f2bf(acc[n][2]); o4.w = f2bf(acc[n][3]);
            *(ushort4*)(ob + (size_t)nid * DIM + colq * 4) = o4;
        }
    }
}

// ======================= K2: fused edge kernel (128 edges/block) ==============
// r-segments padded to 128 -> one r per block; A/M staging (16.9 KB) amortized
// over 128 edges. Each thread loops 4 edges (independent gather chains = ILP).

__global__ __launch_bounds__(256) void k_edge_m3(
    const bf16_t* __restrict__ kbuf, const bf16_t* __restrict__ qbuf,
    const bf16_t* __restrict__ vbuf,
    const int* __restrict__ esrc_s, const int* __restrict__ edst_s,
    const int* __restrict__ rb_pad, const int* __restrict__ dpos,
    const float* __restrict__ rel_att, const float* __restrict__ rel_msg,
    const float* __restrict__ rel_pri,
    float* __restrict__ ex_out, bf16_t* __restrict__ m_out) {
    __shared__ float A2[8 * 260];   // 8.3 KB
    __shared__ float M2[8 * 260];   // 8.3 KB
    __shared__ float pri[8];
    __shared__ int r_s;
    int b = blockIdx.x;
    int e0 = b * EPAD_ALIGN;
    int tid = threadIdx.x;
    if (tid == 0) {
        int r = 0;
#pragma unroll
        for (int q = 1; q < R_TYPES; ++q) if (e0 >= rb_pad[q]) r = q;
        r_s = r;
    }
    __syncthreads();
    int r = r_s;
    for (int idx = tid; idx < 2048; idx += 256) {
        int h = idx >> 8, dj = idx & 255;
        A2[h * 260 + dj] = rel_att[(h * R_TYPES + r) * 256 + dj];
        M2[h * 260 + dj] = rel_msg[(h * R_TYPES + r) * 256 + dj];
    }
    if (tid < 8) pri[tid] = rel_pri[tid * R_TYPES + r] * 0.25f;
    __syncthreads();
    int el = tid >> 3;
    int h  = tid & 7;
    const float4* A4 = (const float4*)&A2[h * 260];
    const float4* M4 = (const float4*)&M2[h * 260];
    float prih = pri[h];

    for (int it = 0; it < EPAD_ALIGN / 32; ++it) {
        int q2 = e0 + it * 32 + el;
        int s = esrc_s[q2];
        if (s < 0) continue;                     // padding sentinel
        int dn = edst_s[q2];
        const uint4* kp = (const uint4*)(kbuf + (size_t)s  * DIM + h * 16);
        const uint4* qp = (const uint4*)(qbuf + (size_t)dn * DIM + h * 16);
        const uint4* vp = (const uint4*)(vbuf + (size_t)s  * DIM + h * 16);
        uint4 ka = kp[0], kb4 = kp[1];
        uint4 qa = qp[0], qb4 = qp[1];
        uint4 va = vp[0], vb4 = vp[1];
        float kk[16], qq[16], vv[16];
        bf2x(ka.x,  kk[0],  kk[1]);  bf2x(ka.y,  kk[2],  kk[3]);
        bf2x(ka.z,  kk[4],  kk[5]);  bf2x(ka.w,  kk[6],  kk[7]);
        bf2x(kb4.x, kk[8],  kk[9]);  bf2x(kb4.y, kk[10], kk[11]);
        bf2x(kb4.z, kk[12], kk[13]); bf2x(kb4.w, kk[14], kk[15]);
        bf2x(qa.x,  qq[0],  qq[1]);  bf2x(qa.y,  qq[2],  qq[3]);
        bf2x(qa.z,  qq[4],  qq[5]);  bf2x(qa.w,  qq[6],  qq[7]);
        bf2x(qb4.x, qq[8],  qq[9]);  bf2x(qb4.y, qq[10], qq[11]);
        bf2x(qb4.z, qq[12], qq[13]); bf2x(qb4.w, qq[14], qq[15]);
        bf2x(va.x,  vv[0],  vv[1]);  bf2x(va.y,  vv[2],  vv[3]);
        bf2x(va.z,  vv[4],  vv[5]);  bf2x(va.w,  vv[6],  vv[7]);
        bf2x(vb4.x, vv[8],  vv[9]);  bf2x(vb4.y, vv[10], vv[11]);
        bf2x(vb4.z, vv[12], vv[13]); bf2x(vb4.w, vv[14], vv[15]);

        // QK^T: accj[j] = sum_d k_d A[d][j]; a = accj . q
        float accj[16];
#pragma unroll
        for (int j = 0; j < 16; ++j) accj[j] = 0.f;
#pragma unroll
        for (int d = 0; d < 16; ++d) {
            float kd = kk[d];
#pragma unroll
            for (int jj = 0; jj < 4; ++jj) {
                float4 a4 = A4[d * 4 + jj];
                accj[jj * 4 + 0] = fmaf(kd, a4.x, accj[jj * 4 + 0]);
                accj[jj * 4 + 1] = fmaf(kd, a4.y, accj[jj * 4 + 1]);
                accj[jj * 4 + 2] = fmaf(kd, a4.z, accj[jj * 4 + 2]);
                accj[jj * 4 + 3] = fmaf(kd, a4.w, accj[jj * 4 + 3]);
            }
        }
        float a = 0.f;
#pragma unroll
        for (int j = 0; j < 16; ++j) a = fmaf(accj[j], qq[j], a);
        float ex = __expf(a * prih - SM_SHIFT);

        // message: m[j] = ex * sum_d v_d M[d][j]
        float mj[16];
#pragma unroll
        for (int j = 0; j < 16; ++j) mj[j] = 0.f;
#pragma unroll
        for (int d = 0; d < 16; ++d) {
            float vd = vv[d];
#pragma unroll
            for (int jj = 0; jj < 4; ++jj) {
                float4 m4 = M4[d * 4 + jj];
                mj[jj * 4 + 0] = fmaf(vd, m4.x, mj[jj * 4 + 0]);
                mj[jj * 4 + 1] = fmaf(vd, m4.y, mj[jj * 4 + 1]);
                mj[jj * 4 + 2] = fmaf(vd, m4.z, mj[jj * 4 + 2]);
                mj[jj * 4 + 3] = fmaf(vd, m4.w, mj[jj * 4 + 3]);
            }
        }
        int dp = dpos[q2];
        ex_out[(size_t)dp * 8 + h] = ex;
        uint4 o0, o1;
        o0.x = pk(ex * mj[0],  ex * mj[1]);  o0.y = pk(ex * mj[2],  ex * mj[3]);
        o0.z = pk(ex * mj[4],  ex * mj[5]);  o0.w = pk(ex * mj[6],  ex * mj[7]);
        o1.x = pk(ex * mj[8],  ex * mj[9]);  o1.y = pk(ex * mj[10], ex * mj[11]);
        o1.z = pk(ex * mj[12], ex * mj[13]); o1.w = pk(ex * mj[14], ex * mj[15]);
        uint4* op = (uint4*)(m_out + (size_t)dp * DIM + h * 16);
        op[0] = o0; op[1] = o1;
    }
}

// ======================= K3: streaming aggregate ==============================

__global__ __launch_bounds__(256) void k_agg_stream(
    const bf16_t* __restrict__ m_out, const float* __restrict__ ex_out,
    const int* __restrict__ doffD, const int* __restrict__ degD,
    float* __restrict__ hacc, int n) {
    int tid = threadIdx.x;
    int nb = tid >> 7;
    int lane2 = tid & 127;
    int node = blockIdx.x * 2 + nb;
    if (node >= n) return;
    int h = lane2 >> 4;
    int off = doffD[node];
    int dg  = degD[node];
    float acc = 0.f, den = 0.f;
#pragma unroll 4
    for (int j = 0; j < dg; ++j) {
        den += ex_out[(size_t)(off + j) * 8 + h];                 // broadcast
        acc += bf2f(m_out[(size_t)(off + j) * DIM + lane2]);      // coalesced row
    }
    hacc[(size_t)node * DIM + lane2] = acc / fmaxf(den, 1e-9f);
}

// ======================= K4: tiled Wa + gate + residual + LayerNorm ===========

__global__ __launch_bounds__(256) void k_final_gemm(
    const float* __restrict__ x, const int* __restrict__ nlist,
    const int* __restrict__ tile_type, const int* __restrict__ ntiles_g,
    const float* __restrict__ Wa, const float* __restrict__ skip,
    const float* __restrict__ gamma, const float* __restrict__ beta,
    float* __restrict__ out) {
    __shared__ float hs[BN][DIM];
    __shared__ float ys[BN][DIM];
    __shared__ int sids[BN];
    __shared__ float mred[BN], ired[BN];
    int b = blockIdx.x;
    if (b >= *ntiles_g) return;
    int tid = threadIdx.x;
    if (tid < BN) sids[tid] = nlist[b * BN + tid];
    __syncthreads();
    for (int idx = tid; idx < BN * DIM; idx += 256) {
        int row = idx >> 7, col = idx & 127;
        int nid = sids[row];
        hs[row][col] = (nid >= 0) ? out[(size_t)nid * DIM + col] : 0.f;
    }
    __syncthreads();
    int t = tile_type[b];
    int half = tid >> 7, col = tid & 127;
    const float* W = Wa + (size_t)t * DIM * DIM;
    float acc[8];
#pragma unroll
    for (int n = 0; n < 8; ++n) acc[n] = 0.f;
#pragma unroll 4
    for (int d = 0; d < DIM; ++d) {
        float w = W[d * DIM + col];
#pragma unroll
        for (int n = 0; n < 8; ++n) acc[n] = fmaf(hs[half * 8 + n][d], w, acc[n]);
    }
    float gte = 1.f / (1.f + __expf(-skip[t]));
#pragma unroll
    for (int n = 0; n < 8; ++n) {
        int row = half * 8 + n;
        int nid = sids[row];
        float xv = (nid >= 0) ? x[(size_t)nid * DIM + col] : 0.f;
        ys[row][col] = xv * (2.f - gte) + acc[n] * gte;
    }
    __syncthreads();
    int ng = tid >> 4, l16 = tid & 15;
    float s = 0.f, s2 = 0.f;
#pragma unroll
    for (int k2 = 0; k2 < 8; ++k2) {
        float yv = ys[ng][l16 + 16 * k2];
        s += yv; s2 += yv * yv;
    }
#pragma unroll
    for (int m = 1; m < 16; m <<= 1) {
        s  += __shfl_xor(s, m, 64);
        s2 += __shfl_xor(s2, m, 64);
    }
    if (l16 == 0) {
        float mu = s * (1.f / DIM);
        float var = s2 * (1.f / DIM) - mu * mu;
        mred[ng] = mu;
        ired[ng] = rsqrtf(var + 1e-5f);
    }
    __syncthreads();
    float gm = gamma[col], bt = beta[col];
#pragma unroll
    for (int n = 0; n < 8; ++n) {
        int row = half * 8 + n;
        int nid = sids[row];
        if (nid >= 0)
            out[(size_t)nid * DIM + col] = (ys[row][col] - mred[row]) * ired[row] * gm + bt;
    }
}

// ======================= launcher =======================

extern "C" void kernel_launch(void* const* d_in, const int* in_sizes, int n_in,
                              void* d_out, int out_size, void* d_ws, size_t ws_size,
                              hipStream_t stream) {
    const float* x       = (const float*)d_in[0];
    const int*   src     = (const int*)d_in[1];
    const int*   dst     = (const int*)d_in[2];
    const int*   ntype   = (const int*)d_in[3];
    const int*   etype   = (const int*)d_in[4];
    const float* Wk      = (const float*)d_in[5];
    const float* Wq      = (const float*)d_in[6];
    const float* Wv      = (const float*)d_in[7];
    const float* Wa      = (const float*)d_in[8];
    const float* rel_pri = (const float*)d_in[9];
    const float* rel_att = (const float*)d_in[10];
    const float* rel_msg = (const float*)d_in[11];
    const float* skip    = (const float*)d_in[12];
    const float* gamma   = (const float*)d_in[13];
    const float* beta    = (const float*)d_in[14];
    float* out = (float*)d_out;

    const int N = N_NODES, E = N_EDGES;

    // workspace layout (deg6, degD, tcnt contiguous so one memset covers them)
    char* ws = (char*)d_ws;
    float* ex_out = (float*)ws;                         // E*8 f32 (12.8 MB)
    int* deg6    = (int*)(ex_out + (size_t)E * H_HEADS);// NKEYS
    int* degD    = deg6 + NKEYS;                        // N
    int* tcnt    = degD + N;                            // T_TYPES
    int* offs6   = tcnt + T_TYPES;                      // NKEYS
    int* partial6 = offs6 + NKEYS;                      // NBLK_K
    int* doffD   = partial6 + NBLK_K;                   // N
    int* partialD = doffD + N;                          // NBLK_N
    int* cursor6 = partialD + NBLK_N;                   // NKEYS
    int* cursorD = cursor6 + NKEYS;                     // N
    int* rb_pad  = cursorD + N;                         // R_TYPES+1
    int* rstart  = rb_pad + R_TYPES + 1;                // R_TYPES
    int* dpos    = rstart + R_TYPES;                    // EPAD_MAX
    int* esrc_s  = dpos + EPAD_MAX;                     // EPAD_MAX
    int* edst_s  = esrc_s + EPAD_MAX;                   // EPAD_MAX
    int* pbase   = edst_s + EPAD_MAX;                   // T_TYPES
    int* ntiles  = pbase + T_TYPES;                     // 1
    int* tile_type = ntiles + 1;                        // MAX_TILES
    int* nlist   = tile_type + MAX_TILES;               // MAX_TILES*BN
    int* wpos    = nlist + (size_t)MAX_TILES * BN;      // N
    bf16_t* kb   = (bf16_t*)(wpos + N);                 // N*DIM bf16
    bf16_t* qb   = kb + (size_t)N * DIM;                // N*DIM
    bf16_t* vb   = qb + (size_t)N * DIM;                // N*DIM
    bf16_t* m_out = vb + (size_t)N * DIM;               // E*DIM bf16 (102.4 MB)

    const int nbE = (E + 255) / 256;

    // counts (one memset covers deg6+degD+tcnt)
    hipMemsetAsync(deg6, 0, (size_t)(NKEYS + N + T_TYPES) * sizeof(int), stream);
    k_count_all<<<nbE, 256, 0, stream>>>(src, dst, etype, deg6, degD, E);
    k_tcount_agg<<<NBLK_N, 256, 0, stream>>>(ntype, tcnt, wpos, N);

    // scans
    k_scanA<<<NBLK_K, 256, 0, stream>>>(deg6, offs6, partial6, NKEYS);
    k_scanA<<<NBLK_N, 256, 0, stream>>>(degD, doffD, partialD, N);
    k_rscan2<<<1, 256, 0, stream>>>(partial6, NBLK_K, partialD, NBLK_N);

    // serial setup: padded r-bases, sentinels, type tiles
    k_small_setup<<<1, 256, 0, stream>>>(
        offs6, partial6, tcnt, rb_pad, rstart, pbase, ntiles, tile_type,
        nlist, esrc_s, E);
    k_cursor_pad<<<NBLK_K, 256, 0, stream>>>(offs6, partial6, rb_pad, rstart, cursor6, NKEYS);
    k_scanC2<<<NBLK_N, 256, 0, stream>>>(doffD, partialD, cursorD, N);

    // scatters
    k_scatter6D<<<nbE, 256, 0, stream>>>(
        src, dst, etype, cursor6, cursorD, esrc_s, edst_s, dpos, E);
    k_tscatter2<<<NBLK_N, 256, 0, stream>>>(ntype, wpos, pbase, nlist, N);

    // projections (tiled per-type GEMM, bf16 outputs)
    k_kqv_gemm4<<<MAX_TILES, 192, 0, stream>>>(
        x, nlist, tile_type, ntiles, Wk, Wq, Wv, kb, qb, vb);

    // fused edge kernel: QK^T, exp, M.v -> dst-major ex/m (128 edges/block)
    k_edge_m3<<<EPAD_MAX / EPAD_ALIGN, 256, 0, stream>>>(
        kb, qb, vb, esrc_s, edst_s, rb_pad, dpos,
        rel_att, rel_msg, rel_pri, ex_out, m_out);

    // streaming per-node aggregate -> d_out (scratch)
    k_agg_stream<<<(N + 1) / 2, 256, 0, stream>>>(
        m_out, ex_out, doffD, degD, out, N);

    // output projection + gate + residual + LayerNorm (in place on d_out)
    k_final_gemm<<<MAX_TILES, 256, 0, stream>>>(
        x, nlist, tile_type, ntiles, Wa, skip, gamma, beta, out);
}

// Round 18
// 335.408 us; speedup vs baseline: 1.1830x; 1.1079x over previous
//
#include <hip/hip_runtime.h>
#include <math.h>

#define N_NODES 50000
#define N_EDGES 400000
#define H_HEADS 8
#define D_HEAD 16
#define R_TYPES 6
#define T_TYPES 4
#define DIM 128
#define BN 16                                      // nodes per GEMM tile
#define MAX_TILES ((N_NODES + BN - 1) / BN + T_TYPES)
#define NKEYS (N_NODES * R_TYPES)                  // 300000 (r,src) buckets, r-major
#define NBLK_K ((NKEYS + 255) / 256)               // 1172
#define NBLK_N ((N_NODES + 255) / 256)             // 196
#define EPAD_ALIGN 128                             // r-segment alignment (= edges/block)
#define EPAD_MAX (N_EDGES + R_TYPES * EPAD_ALIGN)  // 400768
#define SM_SHIFT 8.0f                              // constant softmax shift

typedef unsigned short bf16_t;

__device__ __forceinline__ float bf2f(bf16_t u) {
    unsigned int v = ((unsigned int)u) << 16;
    return __int_as_float((int)v);
}
__device__ __forceinline__ bf16_t f2bf(float f) {
    unsigned int u = (unsigned int)__float_as_int(f);
    unsigned int lsb = (u >> 16) & 1u;
    u += 0x7fffu + lsb;                            // round-to-nearest-even
    return (bf16_t)(u >> 16);
}
__device__ __forceinline__ void bf2x(unsigned int u, float& a, float& b) {
    a = bf2f((bf16_t)(u & 0xffffu));
    b = bf2f((bf16_t)(u >> 16));
}
__device__ __forceinline__ unsigned int pk(float a, float b) {
    return (unsigned int)f2bf(a) | ((unsigned int)f2bf(b) << 16);
}

// ======================= scans =======================

__global__ void k_scanA(const int* __restrict__ cnt, int* __restrict__ offs,
                        int* __restrict__ partial, int n) {
    __shared__ int tmp[256];
    int tid = threadIdx.x;
    int i = blockIdx.x * 256 + tid;
    int v = (i < n) ? cnt[i] : 0;
    tmp[tid] = v;
    __syncthreads();
    for (int o = 1; o < 256; o <<= 1) {
        int t = (tid >= o) ? tmp[tid - o] : 0;
        __syncthreads();
        tmp[tid] += t;
        __syncthreads();
    }
    if (i < n) offs[i] = tmp[tid] - v;           // exclusive within block
    if (tid == 255) partial[blockIdx.x] = tmp[255];
}

__device__ void dev_rscan(int* a, int total, int* tmp, int* carry_s) {
    int tid = threadIdx.x;
    if (tid == 0) *carry_s = 0;
    __syncthreads();
    for (int base = 0; base < total; base += 256) {
        int i = base + tid;
        int v = (i < total) ? a[i] : 0;
        tmp[tid] = v;
        __syncthreads();
        for (int o = 1; o < 256; o <<= 1) {
            int t = (tid >= o) ? tmp[tid - o] : 0;
            __syncthreads();
            tmp[tid] += t;
            __syncthreads();
        }
        int carry = *carry_s;
        if (i < total) a[i] = carry + tmp[tid] - v;   // exclusive
        __syncthreads();
        if (tid == 255) *carry_s = carry + tmp[255];
        __syncthreads();
    }
}

// ======================= fused counts: edge degrees + node-type histogram =====

__global__ void k_count_combo(const int* __restrict__ src, const int* __restrict__ dst,
                              const int* __restrict__ etype, const int* __restrict__ ntype,
                              int* __restrict__ deg6, int* __restrict__ degD,
                              int* __restrict__ tcnt, int* __restrict__ wpos,
                              int nE, int nN) {
    __shared__ int hist[T_TYPES];
    __shared__ int base[T_TYPES];
    int tid = threadIdx.x;
    int i = blockIdx.x * 256 + tid;
    if (tid < T_TYPES) hist[tid] = 0;
    __syncthreads();
    if (i < nE) {
        atomicAdd(&deg6[etype[i] * N_NODES + src[i]], 1);
        atomicAdd(&degD[dst[i]], 1);
    }
    int t = 0, rank = 0;
    if (i < nN) {
        t = ntype[i];
        rank = atomicAdd(&hist[t], 1);
    }
    __syncthreads();
    if (tid < T_TYPES)
        base[tid] = (hist[tid] > 0) ? atomicAdd(&tcnt[tid], hist[tid]) : 0;
    __syncthreads();
    if (i < nN) wpos[i] = base[t] + rank;
}

// ======================= single-block: both partial scans + serial setup ======

__global__ void k_scan_small(int* __restrict__ partial6, int* __restrict__ partialD,
                             const int* __restrict__ offs6, const int* __restrict__ tcnt,
                             int* __restrict__ rb_pad, int* __restrict__ rstart,
                             int* __restrict__ pbase, int* __restrict__ ntiles_g,
                             int* __restrict__ tile_type, int* __restrict__ nlist,
                             int* __restrict__ esrc_s, int nE) {
    __shared__ int tmp[256];
    __shared__ int carry_s;
    __shared__ int rbp[R_TYPES + 1], len[R_TYPES];
    __shared__ int off_t[T_TYPES + 1];
    int tid = threadIdx.x;
    dev_rscan(partial6, NBLK_K, tmp, &carry_s);
    __syncthreads();
    dev_rscan(partialD, NBLK_N, tmp, &carry_s);
    __syncthreads();
    if (tid == 0) {
        int o = 0;
        int st = offs6[0] + partial6[0];
        for (int r = 0; r < R_TYPES; ++r) {
            int idx1 = (r + 1) * N_NODES;
            int en = (r < R_TYPES - 1) ? (offs6[idx1] + partial6[idx1 >> 8]) : nE;
            rstart[r] = st;
            len[r] = en - st;
            rbp[r] = o; rb_pad[r] = o;
            o += (en - st + EPAD_ALIGN - 1) & ~(EPAD_ALIGN - 1);
            st = en;
        }
        rbp[R_TYPES] = o; rb_pad[R_TYPES] = o;
        int o2 = 0;
        for (int t = 0; t < T_TYPES; ++t) {
            off_t[t] = o2;
            pbase[t] = o2 * BN;
            o2 += (tcnt[t] + BN - 1) / BN;
        }
        off_t[T_TYPES] = o2;
        *ntiles_g = o2;
    }
    __syncthreads();
    // esrc sentinels: per-r pad gaps + tail
    for (int r = 0; r < R_TYPES; ++r)
        for (int i = rbp[r] + len[r] + tid; i < rbp[r + 1]; i += 256) esrc_s[i] = -1;
    for (int i = rbp[R_TYPES] + tid; i < EPAD_MAX; i += 256) esrc_s[i] = -1;
    // tile_type fill
    int total = off_t[T_TYPES];
    for (int i = tid; i < total; i += 256) {
        int t = 0;
        while (t < T_TYPES - 1 && i >= off_t[t + 1]) ++t;
        tile_type[i] = t;
    }
    // nlist pad sentinels
    for (int t = 0; t < T_TYPES; ++t) {
        int b0 = off_t[t] * BN + tcnt[t];
        int b1 = off_t[t + 1] * BN;
        for (int i = b0 + tid; i < b1; i += 256) nlist[i] = -1;
    }
}

// ======================= fused cursor init (cursor6 + doffD/cursorD) ==========

__global__ void k_cursor_combo(const int* __restrict__ offs6, const int* __restrict__ partial6,
                               const int* __restrict__ rb_pad, const int* __restrict__ rstart,
                               int* __restrict__ cursor6,
                               int* __restrict__ doffD, const int* __restrict__ partialD,
                               int* __restrict__ cursorD, int nK, int nN) {
    int i = blockIdx.x * 256 + threadIdx.x;
    if (i < nK) {
        int r = i / N_NODES;
        int v = offs6[i] + partial6[i >> 8];
        cursor6[i] = rb_pad[r] + (v - rstart[r]);
    }
    if (i < nN) {
        int v = doffD[i] + partialD[i >> 8];
        doffD[i] = v;
        cursorD[i] = v;
    }
}

// ======================= fused scatters (edges + node tiles) ==================

__global__ void k_scatter_combo(const int* __restrict__ src, const int* __restrict__ dst,
                                const int* __restrict__ etype, const int* __restrict__ ntype,
                                int* __restrict__ cursor6, int* __restrict__ cursorD,
                                int* __restrict__ esrc_s, int* __restrict__ edst_s,
                                int* __restrict__ dpos,
                                const int* __restrict__ wpos, const int* __restrict__ pbase,
                                int* __restrict__ nlist, int nE, int nN) {
    int i = blockIdx.x * 256 + threadIdx.x;
    if (i < nE) {
        int dn = dst[i];
        int key = etype[i] * N_NODES + src[i];
        int pos = atomicAdd(&cursor6[key], 1);
        esrc_s[pos] = src[i];
        edst_s[pos] = dn;
        dpos[pos] = atomicAdd(&cursorD[dn], 1);
    }
    if (i < nN) nlist[pbase[ntype[i]] + wpos[i]] = i;
}

// ======================= K1: tiled typed-linear k,q,v (bf16 out) ==========

__global__ __launch_bounds__(192) void k_kqv_gemm4(
    const float* __restrict__ x, const int* __restrict__ nlist,
    const int* __restrict__ tile_type, const int* __restrict__ ntiles_g,
    const float* __restrict__ Wk, const float* __restrict__ Wq,
    const float* __restrict__ Wv,
    bf16_t* __restrict__ kb, bf16_t* __restrict__ qb, bf16_t* __restrict__ vb) {
    __shared__ float xs[BN][DIM];   // 8 KB
    __shared__ int sids[BN];
    int b = blockIdx.x;
    if (b >= *ntiles_g) return;
    int tid = threadIdx.x;
    if (tid < BN) sids[tid] = nlist[b * BN + tid];
    __syncthreads();
    for (int idx = tid; idx < BN * (DIM / 4); idx += 192) {
        int row = idx >> 5;
        int q4 = idx & 31;
        int nid = sids[row];
        float4 v4 = make_float4(0.f, 0.f, 0.f, 0.f);
        if (nid >= 0) v4 = *(const float4*)(x + (size_t)nid * DIM + q4 * 4);
        *(float4*)(&xs[row][q4 * 4]) = v4;
    }
    __syncthreads();
    int lt = tid / 96;
    int wi = tid % 96;
    int mat = wi >> 5;
    int colq = wi & 31;
    int t = tile_type[b];
    const float* W = (mat == 0 ? Wk : (mat == 1 ? Wq : Wv))
                     + (size_t)t * DIM * DIM + colq * 4;
    float acc[8][4];
#pragma unroll
    for (int n = 0; n < 8; ++n) {
        acc[n][0] = 0.f; acc[n][1] = 0.f; acc[n][2] = 0.f; acc[n][3] = 0.f;
    }
    const float* xbase = &xs[lt * 8][0];
    for (int dq = 0; dq < 32; ++dq) {
        float4 w0 = *(const float4*)(W + (size_t)(dq * 4 + 0) * DIM);
        float4 w1 = *(const float4*)(W + (size_t)(dq * 4 + 1) * DIM);
        float4 w2 = *(const float4*)(W + (size_t)(dq * 4 + 2) * DIM);
        float4 w3 = *(const float4*)(W + (size_t)(dq * 4 + 3) * DIM);
#pragma unroll
        for (int n = 0; n < 8; ++n) {
            float4 xv = *(const float4*)(xbase + n * DIM + dq * 4);
            acc[n][0] = fmaf(xv.x, w0.x, acc[n][0]);
            acc[n][0] = fmaf(xv.y, w1.x, acc[n][0]);
            acc[n][0] = fmaf(xv.z, w2.x, acc[n][0]);
            acc[n][0] = fmaf(xv.w, w3.x, acc[n][0]);
            acc[n][1] = fmaf(xv.x, w0.y, acc[n][1]);
            acc[n][1] = fmaf(xv.y, w1.y, acc[n][1]);
            acc[n][1] = fmaf(xv.z, w2.y, acc[n][1]);
            acc[n][1] = fmaf(xv.w, w3.y, acc[n][1]);
            acc[n][2] = fmaf(xv.x, w0.z, acc[n][2]);
            acc[n][2] = fmaf(xv.y, w1.z, acc[n][2]);
            acc[n][2] = fmaf(xv.z, w2.z, acc[n][2]);
            acc[n][2] = fmaf(xv.w, w3.z, acc[n][2]);
            acc[n][3] = fmaf(xv.x, w0.w, acc[n][3]);
            acc[n][3] = fmaf(xv.y, w1.w, acc[n][3]);
            acc[n][3] = fmaf(xv.z, w2.w, acc[n][3]);
            acc[n][3] = fmaf(xv.w, w3.w, acc[n][3]);
        }
    }
    bf16_t* ob = (mat == 0 ? kb : (mat == 1 ? qb : vb));
#pragma unroll
    for (int n = 0; n < 8; ++n) {
        int nid = sids[lt * 8 + n];
        if (nid >= 0) {
            ushort4 o4;
            o4.x = f2bf(acc[n][0]); o4.y = f2bf(acc[n][1]);
            o4.z = f2bf(acc[n][2]); o4.w = f2bf(acc[n][3]);
            *(ushort4*)(ob + (size_t)nid * DIM + colq * 4) = o4;
        }
    }
}

// ======================= K2: fused edge kernel (128 edges/block) ==============

__global__ __launch_bounds__(256) void k_edge_m3(
    const bf16_t* __restrict__ kbuf, const bf16_t* __restrict__ qbuf,
    const bf16_t* __restrict__ vbuf,
    const int* __restrict__ esrc_s, const int* __restrict__ edst_s,
    const int* __restrict__ rb_pad, const int* __restrict__ dpos,
    const float* __restrict__ rel_att, const float* __restrict__ rel_msg,
    const float* __restrict__ rel_pri,
    float* __restrict__ ex_out, bf16_t* __restrict__ m_out) {
    __shared__ float A2[8 * 260];   // 8.3 KB
    __shared__ float M2[8 * 260];   // 8.3 KB
    __shared__ float pri[8];
    __shared__ int r_s;
    int b = blockIdx.x;
    int e0 = b * EPAD_ALIGN;
    int tid = threadIdx.x;
    if (tid == 0) {
        int r = 0;
#pragma unroll
        for (int q = 1; q < R_TYPES; ++q) if (e0 >= rb_pad[q]) r = q;
        r_s = r;
    }
    __syncthreads();
    int r = r_s;
    for (int idx = tid; idx < 2048; idx += 256) {
        int h = idx >> 8, dj = idx & 255;
        A2[h * 260 + dj] = rel_att[(h * R_TYPES + r) * 256 + dj];
        M2[h * 260 + dj] = rel_msg[(h * R_TYPES + r) * 256 + dj];
    }
    if (tid < 8) pri[tid] = rel_pri[tid * R_TYPES + r] * 0.25f;
    __syncthreads();
    int el = tid >> 3;
    int h  = tid & 7;
    const float4* A4 = (const float4*)&A2[h * 260];
    const float4* M4 = (const float4*)&M2[h * 260];
    float prih = pri[h];

    for (int it = 0; it < EPAD_ALIGN / 32; ++it) {
        int q2 = e0 + it * 32 + el;
        int s = esrc_s[q2];
        if (s < 0) continue;                     // padding sentinel
        int dn = edst_s[q2];
        const uint4* kp = (const uint4*)(kbuf + (size_t)s  * DIM + h * 16);
        const uint4* qp = (const uint4*)(qbuf + (size_t)dn * DIM + h * 16);
        const uint4* vp = (const uint4*)(vbuf + (size_t)s  * DIM + h * 16);
        uint4 ka = kp[0], kb4 = kp[1];
        uint4 qa = qp[0], qb4 = qp[1];
        uint4 va = vp[0], vb4 = vp[1];
        float kk[16], qq[16], vv[16];
        bf2x(ka.x,  kk[0],  kk[1]);  bf2x(ka.y,  kk[2],  kk[3]);
        bf2x(ka.z,  kk[4],  kk[5]);  bf2x(ka.w,  kk[6],  kk[7]);
        bf2x(kb4.x, kk[8],  kk[9]);  bf2x(kb4.y, kk[10], kk[11]);
        bf2x(kb4.z, kk[12], kk[13]); bf2x(kb4.w, kk[14], kk[15]);
        bf2x(qa.x,  qq[0],  qq[1]);  bf2x(qa.y,  qq[2],  qq[3]);
        bf2x(qa.z,  qq[4],  qq[5]);  bf2x(qa.w,  qq[6],  qq[7]);
        bf2x(qb4.x, qq[8],  qq[9]);  bf2x(qb4.y, qq[10], qq[11]);
        bf2x(qb4.z, qq[12], qq[13]); bf2x(qb4.w, qq[14], qq[15]);
        bf2x(va.x,  vv[0],  vv[1]);  bf2x(va.y,  vv[2],  vv[3]);
        bf2x(va.z,  vv[4],  vv[5]);  bf2x(va.w,  vv[6],  vv[7]);
        bf2x(vb4.x, vv[8],  vv[9]);  bf2x(vb4.y, vv[10], vv[11]);
        bf2x(vb4.z, vv[12], vv[13]); bf2x(vb4.w, vv[14], vv[15]);

        // QK^T: accj[j] = sum_d k_d A[d][j]; a = accj . q
        float accj[16];
#pragma unroll
        for (int j = 0; j < 16; ++j) accj[j] = 0.f;
#pragma unroll
        for (int d = 0; d < 16; ++d) {
            float kd = kk[d];
#pragma unroll
            for (int jj = 0; jj < 4; ++jj) {
                float4 a4 = A4[d * 4 + jj];
                accj[jj * 4 + 0] = fmaf(kd, a4.x, accj[jj * 4 + 0]);
                accj[jj * 4 + 1] = fmaf(kd, a4.y, accj[jj * 4 + 1]);
                accj[jj * 4 + 2] = fmaf(kd, a4.z, accj[jj * 4 + 2]);
                accj[jj * 4 + 3] = fmaf(kd, a4.w, accj[jj * 4 + 3]);
            }
        }
        float a = 0.f;
#pragma unroll
        for (int j = 0; j < 16; ++j) a = fmaf(accj[j], qq[j], a);
        float ex = __expf(a * prih - SM_SHIFT);

        // message: m[j] = ex * sum_d v_d M[d][j]
        float mj[16];
#pragma unroll
        for (int j = 0; j < 16; ++j) mj[j] = 0.f;
#pragma unroll
        for (int d = 0; d < 16; ++d) {
            float vd = vv[d];
#pragma unroll
            for (int jj = 0; jj < 4; ++jj) {
                float4 m4 = M4[d * 4 + jj];
                mj[jj * 4 + 0] = fmaf(vd, m4.x, mj[jj * 4 + 0]);
                mj[jj * 4 + 1] = fmaf(vd, m4.y, mj[jj * 4 + 1]);
                mj[jj * 4 + 2] = fmaf(vd, m4.z, mj[jj * 4 + 2]);
                mj[jj * 4 + 3] = fmaf(vd, m4.w, mj[jj * 4 + 3]);
            }
        }
        int dp = dpos[q2];
        ex_out[(size_t)dp * 8 + h] = ex;
        uint4 o0, o1;
        o0.x = pk(ex * mj[0],  ex * mj[1]);  o0.y = pk(ex * mj[2],  ex * mj[3]);
        o0.z = pk(ex * mj[4],  ex * mj[5]);  o0.w = pk(ex * mj[6],  ex * mj[7]);
        o1.x = pk(ex * mj[8],  ex * mj[9]);  o1.y = pk(ex * mj[10], ex * mj[11]);
        o1.z = pk(ex * mj[12], ex * mj[13]); o1.w = pk(ex * mj[14], ex * mj[15]);
        uint4* op = (uint4*)(m_out + (size_t)dp * DIM + h * 16);
        op[0] = o0; op[1] = o1;
    }
}

// ======================= K3: fused aggregate + Wa + gate + LayerNorm ==========
// Per type-tile block: stream each node's contiguous m_out/ex_out run into the
// h-tile in LDS (16 threads/node), then Wa matvec + gate + residual + LN.

__global__ __launch_bounds__(256) void k_final2(
    const float* __restrict__ x, const int* __restrict__ nlist,
    const int* __restrict__ tile_type, const int* __restrict__ ntiles_g,
    const bf16_t* __restrict__ m_out, const float* __restrict__ ex_out,
    const int* __restrict__ doffD, const int* __restrict__ degD,
    const float* __restrict__ Wa, const float* __restrict__ skip,
    const float* __restrict__ gamma, const float* __restrict__ beta,
    float* __restrict__ out) {
    __shared__ float hs[BN][DIM];
    __shared__ float ys[BN][DIM];
    __shared__ int sids[BN];
    __shared__ float mred[BN], ired[BN];
    int b = blockIdx.x;
    if (b >= *ntiles_g) return;
    int tid = threadIdx.x;
    if (tid < BN) sids[tid] = nlist[b * BN + tid];
    __syncthreads();
    // ---- aggregate: 16 nodes x 16 threads; thread covers elems 8d..8d+7 ----
    {
        int row = tid >> 4, d = tid & 15;
        int nid = sids[row];
        float a0=0.f,a1=0.f,a2=0.f,a3=0.f,a4=0.f,a5=0.f,a6=0.f,a7=0.f;
        float den = 0.f;
        if (nid >= 0) {
            int off = doffD[nid];
            int dg  = degD[nid];
            int hh = d >> 1;
#pragma unroll 2
            for (int j = 0; j < dg; ++j) {
                den += ex_out[(size_t)(off + j) * 8 + hh];
                uint4 mv = *(const uint4*)(m_out + (size_t)(off + j) * DIM + d * 8);
                float u, w;
                bf2x(mv.x, u, w); a0 += u; a1 += w;
                bf2x(mv.y, u, w); a2 += u; a3 += w;
                bf2x(mv.z, u, w); a4 += u; a5 += w;
                bf2x(mv.w, u, w); a6 += u; a7 += w;
            }
        }
        float inv = 1.f / fmaxf(den, 1e-9f);
        float* hp = &hs[row][d * 8];
        hp[0] = a0 * inv; hp[1] = a1 * inv; hp[2] = a2 * inv; hp[3] = a3 * inv;
        hp[4] = a4 * inv; hp[5] = a5 * inv; hp[6] = a6 * inv; hp[7] = a7 * inv;
    }
    __syncthreads();
    // ---- Wa matvec + gate + residual ----
    int t = tile_type[b];
    int half = tid >> 7, col = tid & 127;
    const float* W = Wa + (size_t)t * DIM * DIM;
    float acc[8];
#pragma unroll
    for (int n = 0; n < 8; ++n) acc[n] = 0.f;
#pragma unroll 4
    for (int d = 0; d < DIM; ++d) {
        float w = W[d * DIM + col];
#pragma unroll
        for (int n = 0; n < 8; ++n) acc[n] = fmaf(hs[half * 8 + n][d], w, acc[n]);
    }
    float gte = 1.f / (1.f + __expf(-skip[t]));
#pragma unroll
    for (int n = 0; n < 8; ++n) {
        int row = half * 8 + n;
        int nid = sids[row];
        float xv = (nid >= 0) ? x[(size_t)nid * DIM + col] : 0.f;
        ys[row][col] = xv * (2.f - gte) + acc[n] * gte;   // x + h*g + x*(1-g)
    }
    __syncthreads();
    // ---- LayerNorm ----
    int ng = tid >> 4, l16 = tid & 15;
    float s = 0.f, s2 = 0.f;
#pragma unroll
    for (int k2 = 0; k2 < 8; ++k2) {
        float yv = ys[ng][l16 + 16 * k2];
        s += yv; s2 += yv * yv;
    }
#pragma unroll
    for (int m = 1; m < 16; m <<= 1) {
        s  += __shfl_xor(s, m, 64);
        s2 += __shfl_xor(s2, m, 64);
    }
    if (l16 == 0) {
        float mu = s * (1.f / DIM);
        float var = s2 * (1.f / DIM) - mu * mu;
        mred[ng] = mu;
        ired[ng] = rsqrtf(var + 1e-5f);
    }
    __syncthreads();
    float gm = gamma[col], bt = beta[col];
#pragma unroll
    for (int n = 0; n < 8; ++n) {
        int row = half * 8 + n;
        int nid = sids[row];
        if (nid >= 0)
            out[(size_t)nid * DIM + col] = (ys[row][col] - mred[row]) * ired[row] * gm + bt;
    }
}

// ======================= launcher =======================

extern "C" void kernel_launch(void* const* d_in, const int* in_sizes, int n_in,
                              void* d_out, int out_size, void* d_ws, size_t ws_size,
                              hipStream_t stream) {
    const float* x       = (const float*)d_in[0];
    const int*   src     = (const int*)d_in[1];
    const int*   dst     = (const int*)d_in[2];
    const int*   ntype   = (const int*)d_in[3];
    const int*   etype   = (const int*)d_in[4];
    const float* Wk      = (const float*)d_in[5];
    const float* Wq      = (const float*)d_in[6];
    const float* Wv      = (const float*)d_in[7];
    const float* Wa      = (const float*)d_in[8];
    const float* rel_pri = (const float*)d_in[9];
    const float* rel_att = (const float*)d_in[10];
    const float* rel_msg = (const float*)d_in[11];
    const float* skip    = (const float*)d_in[12];
    const float* gamma   = (const float*)d_in[13];
    const float* beta    = (const float*)d_in[14];
    float* out = (float*)d_out;

    const int N = N_NODES, E = N_EDGES;

    // workspace layout (deg6, degD, tcnt contiguous so one memset covers them)
    char* ws = (char*)d_ws;
    float* ex_out = (float*)ws;                         // E*8 f32 (12.8 MB)
    int* deg6    = (int*)(ex_out + (size_t)E * H_HEADS);// NKEYS
    int* degD    = deg6 + NKEYS;                        // N
    int* tcnt    = degD + N;                            // T_TYPES
    int* offs6   = tcnt + T_TYPES;                      // NKEYS
    int* partial6 = offs6 + NKEYS;                      // NBLK_K
    int* doffD   = partial6 + NBLK_K;                   // N
    int* partialD = doffD + N;                          // NBLK_N
    int* cursor6 = partialD + NBLK_N;                   // NKEYS
    int* cursorD = cursor6 + NKEYS;                     // N
    int* rb_pad  = cursorD + N;                         // R_TYPES+1
    int* rstart  = rb_pad + R_TYPES + 1;                // R_TYPES
    int* dpos    = rstart + R_TYPES;                    // EPAD_MAX
    int* esrc_s  = dpos + EPAD_MAX;                     // EPAD_MAX
    int* edst_s  = esrc_s + EPAD_MAX;                   // EPAD_MAX
    int* pbase   = edst_s + EPAD_MAX;                   // T_TYPES
    int* ntiles  = pbase + T_TYPES;                     // 1
    int* tile_type = ntiles + 1;                        // MAX_TILES
    int* nlist   = tile_type + MAX_TILES;               // MAX_TILES*BN
    int* wpos    = nlist + (size_t)MAX_TILES * BN;      // N
    bf16_t* kb   = (bf16_t*)(wpos + N);                 // N*DIM bf16
    bf16_t* qb   = kb + (size_t)N * DIM;                // N*DIM
    bf16_t* vb   = qb + (size_t)N * DIM;                // N*DIM
    bf16_t* m_out = vb + (size_t)N * DIM;               // E*DIM bf16 (102.4 MB)

    const int nbE = (E + 255) / 256;

    // counts (one memset covers deg6+degD+tcnt; combo also builds wpos)
    hipMemsetAsync(deg6, 0, (size_t)(NKEYS + N + T_TYPES) * sizeof(int), stream);
    k_count_combo<<<nbE, 256, 0, stream>>>(
        src, dst, etype, ntype, deg6, degD, tcnt, wpos, E, N);

    // scans
    k_scanA<<<NBLK_K, 256, 0, stream>>>(deg6, offs6, partial6, NKEYS);
    k_scanA<<<NBLK_N, 256, 0, stream>>>(degD, doffD, partialD, N);
    k_scan_small<<<1, 256, 0, stream>>>(
        partial6, partialD, offs6, tcnt, rb_pad, rstart, pbase, ntiles,
        tile_type, nlist, esrc_s, E);

    // cursors (cursor6 + doffD finalize + cursorD)
    k_cursor_combo<<<NBLK_K, 256, 0, stream>>>(
        offs6, partial6, rb_pad, rstart, cursor6, doffD, partialD, cursorD,
        NKEYS, N);

    // scatters (edges + node tiles)
    k_scatter_combo<<<nbE, 256, 0, stream>>>(
        src, dst, etype, ntype, cursor6, cursorD, esrc_s, edst_s, dpos,
        wpos, pbase, nlist, E, N);

    // projections (tiled per-type GEMM, bf16 outputs)
    k_kqv_gemm4<<<MAX_TILES, 192, 0, stream>>>(
        x, nlist, tile_type, ntiles, Wk, Wq, Wv, kb, qb, vb);

    // fused edge kernel: QK^T, exp, M.v -> dst-major ex/m (128 edges/block)
    k_edge_m3<<<EPAD_MAX / EPAD_ALIGN, 256, 0, stream>>>(
        kb, qb, vb, esrc_s, edst_s, rb_pad, dpos,
        rel_att, rel_msg, rel_pri, ex_out, m_out);

    // fused aggregate + output projection + gate + residual + LayerNorm
    k_final2<<<MAX_TILES, 256, 0, stream>>>(
        x, nlist, tile_type, ntiles, m_out, ex_out, doffD, degD,
        Wa, skip, gamma, beta, out);
}

// Round 19
// 329.954 us; speedup vs baseline: 1.2026x; 1.0165x over previous
//
#include <hip/hip_runtime.h>
#include <math.h>

#define N_NODES 50000
#define N_EDGES 400000
#define H_HEADS 8
#define D_HEAD 16
#define R_TYPES 6
#define T_TYPES 4
#define DIM 128
#define BN 16                                      // nodes per GEMM tile
#define MAX_TILES ((N_NODES + BN - 1) / BN + T_TYPES)
#define NKEYS (N_NODES * R_TYPES)                  // 300000 (r,src) buckets, r-major
#define NBLK_K ((NKEYS + 255) / 256)               // 1172
#define NBLK_N ((N_NODES + 255) / 256)             // 196
#define EPAD_ALIGN 128                             // r-segment alignment (= edges/block)
#define EPAD_MAX (N_EDGES + R_TYPES * EPAD_ALIGN)  // 400768
#define SM_SHIFT 8.0f                              // constant softmax shift

typedef unsigned short bf16_t;

__device__ __forceinline__ float bf2f(bf16_t u) {
    unsigned int v = ((unsigned int)u) << 16;
    return __int_as_float((int)v);
}
__device__ __forceinline__ bf16_t f2bf(float f) {
    unsigned int u = (unsigned int)__float_as_int(f);
    unsigned int lsb = (u >> 16) & 1u;
    u += 0x7fffu + lsb;                            // round-to-nearest-even
    return (bf16_t)(u >> 16);
}
__device__ __forceinline__ void bf2x(unsigned int u, float& a, float& b) {
    a = bf2f((bf16_t)(u & 0xffffu));
    b = bf2f((bf16_t)(u >> 16));
}
__device__ __forceinline__ unsigned int pk(float a, float b) {
    return (unsigned int)f2bf(a) | ((unsigned int)f2bf(b) << 16);
}

// ======================= scans =======================
// fused block-scan: blocks [0,NBLK_K) scan deg6, blocks [NBLK_K,+NBLK_N) scan degD

__global__ void k_scanAB(const int* __restrict__ cnt6, int* __restrict__ offs6,
                         int* __restrict__ partial6,
                         const int* __restrict__ cntD, int* __restrict__ offsD,
                         int* __restrict__ partialD) {
    __shared__ int tmp[256];
    int blk = blockIdx.x;
    const int* cnt; int* offs; int* partial; int n; int bb;
    if (blk < NBLK_K) { cnt = cnt6; offs = offs6; partial = partial6; n = NKEYS; bb = blk; }
    else { cnt = cntD; offs = offsD; partial = partialD; n = N_NODES; bb = blk - NBLK_K; }
    int tid = threadIdx.x;
    int i = bb * 256 + tid;
    int v = (i < n) ? cnt[i] : 0;
    tmp[tid] = v;
    __syncthreads();
    for (int o = 1; o < 256; o <<= 1) {
        int t = (tid >= o) ? tmp[tid - o] : 0;
        __syncthreads();
        tmp[tid] += t;
        __syncthreads();
    }
    if (i < n) offs[i] = tmp[tid] - v;           // exclusive within block
    if (tid == 255) partial[bb] = tmp[255];
}

__device__ void dev_rscan(int* a, int total, int* tmp, int* carry_s) {
    int tid = threadIdx.x;
    if (tid == 0) *carry_s = 0;
    __syncthreads();
    for (int base = 0; base < total; base += 256) {
        int i = base + tid;
        int v = (i < total) ? a[i] : 0;
        tmp[tid] = v;
        __syncthreads();
        for (int o = 1; o < 256; o <<= 1) {
            int t = (tid >= o) ? tmp[tid - o] : 0;
            __syncthreads();
            tmp[tid] += t;
            __syncthreads();
        }
        int carry = *carry_s;
        if (i < total) a[i] = carry + tmp[tid] - v;   // exclusive
        __syncthreads();
        if (tid == 255) *carry_s = carry + tmp[255];
        __syncthreads();
    }
}

// ======================= fused counts: edge degrees + node-type histogram =====

__global__ void k_count_combo(const int* __restrict__ src, const int* __restrict__ dst,
                              const int* __restrict__ etype, const int* __restrict__ ntype,
                              int* __restrict__ deg6, int* __restrict__ degD,
                              int* __restrict__ tcnt, int* __restrict__ wpos,
                              int nE, int nN) {
    __shared__ int hist[T_TYPES];
    __shared__ int base[T_TYPES];
    int tid = threadIdx.x;
    int i = blockIdx.x * 256 + tid;
    if (tid < T_TYPES) hist[tid] = 0;
    __syncthreads();
    if (i < nE) {
        atomicAdd(&deg6[etype[i] * N_NODES + src[i]], 1);
        atomicAdd(&degD[dst[i]], 1);
    }
    int t = 0, rank = 0;
    if (i < nN) {
        t = ntype[i];
        rank = atomicAdd(&hist[t], 1);
    }
    __syncthreads();
    if (tid < T_TYPES)
        base[tid] = (hist[tid] > 0) ? atomicAdd(&tcnt[tid], hist[tid]) : 0;
    __syncthreads();
    if (i < nN) wpos[i] = base[t] + rank;
}

// ======================= single-block: both partial scans + serial setup ======

__global__ void k_scan_small(int* __restrict__ partial6, int* __restrict__ partialD,
                             const int* __restrict__ offs6, const int* __restrict__ tcnt,
                             int* __restrict__ rb_pad, int* __restrict__ rstart,
                             int* __restrict__ pbase, int* __restrict__ ntiles_g,
                             int* __restrict__ tile_type, int* __restrict__ nlist,
                             int* __restrict__ esrc_s, int nE) {
    __shared__ int tmp[256];
    __shared__ int carry_s;
    __shared__ int rbp[R_TYPES + 1], len[R_TYPES];
    __shared__ int off_t[T_TYPES + 1];
    int tid = threadIdx.x;
    dev_rscan(partial6, NBLK_K, tmp, &carry_s);
    __syncthreads();
    dev_rscan(partialD, NBLK_N, tmp, &carry_s);
    __syncthreads();
    if (tid == 0) {
        int o = 0;
        int st = offs6[0] + partial6[0];
        for (int r = 0; r < R_TYPES; ++r) {
            int idx1 = (r + 1) * N_NODES;
            int en = (r < R_TYPES - 1) ? (offs6[idx1] + partial6[idx1 >> 8]) : nE;
            rstart[r] = st;
            len[r] = en - st;
            rbp[r] = o; rb_pad[r] = o;
            o += (en - st + EPAD_ALIGN - 1) & ~(EPAD_ALIGN - 1);
            st = en;
        }
        rbp[R_TYPES] = o; rb_pad[R_TYPES] = o;
        int o2 = 0;
        for (int t = 0; t < T_TYPES; ++t) {
            off_t[t] = o2;
            pbase[t] = o2 * BN;
            o2 += (tcnt[t] + BN - 1) / BN;
        }
        off_t[T_TYPES] = o2;
        *ntiles_g = o2;
    }
    __syncthreads();
    // esrc sentinels: per-r pad gaps + tail
    for (int r = 0; r < R_TYPES; ++r)
        for (int i = rbp[r] + len[r] + tid; i < rbp[r + 1]; i += 256) esrc_s[i] = -1;
    for (int i = rbp[R_TYPES] + tid; i < EPAD_MAX; i += 256) esrc_s[i] = -1;
    // tile_type fill
    int total = off_t[T_TYPES];
    for (int i = tid; i < total; i += 256) {
        int t = 0;
        while (t < T_TYPES - 1 && i >= off_t[t + 1]) ++t;
        tile_type[i] = t;
    }
    // nlist pad sentinels
    for (int t = 0; t < T_TYPES; ++t) {
        int b0 = off_t[t] * BN + tcnt[t];
        int b1 = off_t[t + 1] * BN;
        for (int i = b0 + tid; i < b1; i += 256) nlist[i] = -1;
    }
}

// ======================= fused cursor init (cursor6 + doffD/cursorD) ==========

__global__ void k_cursor_combo(const int* __restrict__ offs6, const int* __restrict__ partial6,
                               const int* __restrict__ rb_pad, const int* __restrict__ rstart,
                               int* __restrict__ cursor6,
                               int* __restrict__ doffD, const int* __restrict__ partialD,
                               int* __restrict__ cursorD, int nK, int nN) {
    int i = blockIdx.x * 256 + threadIdx.x;
    if (i < nK) {
        int r = i / N_NODES;
        int v = offs6[i] + partial6[i >> 8];
        cursor6[i] = rb_pad[r] + (v - rstart[r]);
    }
    if (i < nN) {
        int v = doffD[i] + partialD[i >> 8];
        doffD[i] = v;
        cursorD[i] = v;
    }
}

// ======================= fused scatters (edges + node tiles) ==================

__global__ void k_scatter_combo(const int* __restrict__ src, const int* __restrict__ dst,
                                const int* __restrict__ etype, const int* __restrict__ ntype,
                                int* __restrict__ cursor6, int* __restrict__ cursorD,
                                int* __restrict__ esrc_s, int* __restrict__ edst_s,
                                int* __restrict__ dpos,
                                const int* __restrict__ wpos, const int* __restrict__ pbase,
                                int* __restrict__ nlist, int nE, int nN) {
    int i = blockIdx.x * 256 + threadIdx.x;
    if (i < nE) {
        int dn = dst[i];
        int key = etype[i] * N_NODES + src[i];
        int pos = atomicAdd(&cursor6[key], 1);
        esrc_s[pos] = src[i];
        edst_s[pos] = dn;
        dpos[pos] = atomicAdd(&cursorD[dn], 1);
    }
    if (i < nN) nlist[pbase[ntype[i]] + wpos[i]] = i;
}

// ======================= K1: tiled typed-linear k,q,v (bf16 out) ==========

__global__ __launch_bounds__(192) void k_kqv_gemm4(
    const float* __restrict__ x, const int* __restrict__ nlist,
    const int* __restrict__ tile_type, const int* __restrict__ ntiles_g,
    const float* __restrict__ Wk, const float* __restrict__ Wq,
    const float* __restrict__ Wv,
    bf16_t* __restrict__ kb, bf16_t* __restrict__ qb, bf16_t* __restrict__ vb) {
    __shared__ float xs[BN][DIM];   // 8 KB
    __shared__ int sids[BN];
    int b = blockIdx.x;
    if (b >= *ntiles_g) return;
    int tid = threadIdx.x;
    if (tid < BN) sids[tid] = nlist[b * BN + tid];
    __syncthreads();
    for (int idx = tid; idx < BN * (DIM / 4); idx += 192) {
        int row = idx >> 5;
        int q4 = idx & 31;
        int nid = sids[row];
        float4 v4 = make_float4(0.f, 0.f, 0.f, 0.f);
        if (nid >= 0) v4 = *(const float4*)(x + (size_t)nid * DIM + q4 * 4);
        *(float4*)(&xs[row][q4 * 4]) = v4;
    }
    __syncthreads();
    int lt = tid / 96;
    int wi = tid % 96;
    int mat = wi >> 5;
    int colq = wi & 31;
    int t = tile_type[b];
    const float* W = (mat == 0 ? Wk : (mat == 1 ? Wq : Wv))
                     + (size_t)t * DIM * DIM + colq * 4;
    float acc[8][4];
#pragma unroll
    for (int n = 0; n < 8; ++n) {
        acc[n][0] = 0.f; acc[n][1] = 0.f; acc[n][2] = 0.f; acc[n][3] = 0.f;
    }
    const float* xbase = &xs[lt * 8][0];
    for (int dq = 0; dq < 32; ++dq) {
        float4 w0 = *(const float4*)(W + (size_t)(dq * 4 + 0) * DIM);
        float4 w1 = *(const float4*)(W + (size_t)(dq * 4 + 1) * DIM);
        float4 w2 = *(const float4*)(W + (size_t)(dq * 4 + 2) * DIM);
        float4 w3 = *(const float4*)(W + (size_t)(dq * 4 + 3) * DIM);
#pragma unroll
        for (int n = 0; n < 8; ++n) {
            float4 xv = *(const float4*)(xbase + n * DIM + dq * 4);
            acc[n][0] = fmaf(xv.x, w0.x, acc[n][0]);
            acc[n][0] = fmaf(xv.y, w1.x, acc[n][0]);
            acc[n][0] = fmaf(xv.z, w2.x, acc[n][0]);
            acc[n][0] = fmaf(xv.w, w3.x, acc[n][0]);
            acc[n][1] = fmaf(xv.x, w0.y, acc[n][1]);
            acc[n][1] = fmaf(xv.y, w1.y, acc[n][1]);
            acc[n][1] = fmaf(xv.z, w2.y, acc[n][1]);
            acc[n][1] = fmaf(xv.w, w3.y, acc[n][1]);
            acc[n][2] = fmaf(xv.x, w0.z, acc[n][2]);
            acc[n][2] = fmaf(xv.y, w1.z, acc[n][2]);
            acc[n][2] = fmaf(xv.z, w2.z, acc[n][2]);
            acc[n][2] = fmaf(xv.w, w3.z, acc[n][2]);
            acc[n][3] = fmaf(xv.x, w0.w, acc[n][3]);
            acc[n][3] = fmaf(xv.y, w1.w, acc[n][3]);
            acc[n][3] = fmaf(xv.z, w2.w, acc[n][3]);
            acc[n][3] = fmaf(xv.w, w3.w, acc[n][3]);
        }
    }
    bf16_t* ob = (mat == 0 ? kb : (mat == 1 ? qb : vb));
#pragma unroll
    for (int n = 0; n < 8; ++n) {
        int nid = sids[lt * 8 + n];
        if (nid >= 0) {
            ushort4 o4;
            o4.x = f2bf(acc[n][0]); o4.y = f2bf(acc[n][1]);
            o4.z = f2bf(acc[n][2]); o4.w = f2bf(acc[n][3]);
            *(ushort4*)(ob + (size_t)nid * DIM + colq * 4) = o4;
        }
    }
}

// ======================= K2: fused edge kernel (128 edges/block, v4) ==========
// Indices (esrc/edst/dpos) staged to LDS once per block -> gather addresses are
// LDS-resident, so unroll-2 lets the compiler hoist next iteration's k/q/v
// gathers over the current iteration's ~570-op compute chain.

__global__ __launch_bounds__(256) void k_edge_m4(
    const bf16_t* __restrict__ kbuf, const bf16_t* __restrict__ qbuf,
    const bf16_t* __restrict__ vbuf,
    const int* __restrict__ esrc_s, const int* __restrict__ edst_s,
    const int* __restrict__ rb_pad, const int* __restrict__ dpos,
    const float* __restrict__ rel_att, const float* __restrict__ rel_msg,
    const float* __restrict__ rel_pri,
    float* __restrict__ ex_out, bf16_t* __restrict__ m_out) {
    __shared__ float A2[8 * 260];   // 8.3 KB
    __shared__ float M2[8 * 260];   // 8.3 KB
    __shared__ float pri[8];
    __shared__ int sl[EPAD_ALIGN], dl[EPAD_ALIGN], pl[EPAD_ALIGN];  // 1.5 KB
    __shared__ int r_s;
    int b = blockIdx.x;
    int e0 = b * EPAD_ALIGN;
    int tid = threadIdx.x;
    if (tid == 0) {
        int r = 0;
#pragma unroll
        for (int q = 1; q < R_TYPES; ++q) if (e0 >= rb_pad[q]) r = q;
        r_s = r;
    }
    if (tid < EPAD_ALIGN) {
        sl[tid] = esrc_s[e0 + tid];
        dl[tid] = edst_s[e0 + tid];
        pl[tid] = dpos[e0 + tid];
    }
    __syncthreads();
    int r = r_s;
    for (int idx = tid; idx < 2048; idx += 256) {
        int h = idx >> 8, dj = idx & 255;
        A2[h * 260 + dj] = rel_att[(h * R_TYPES + r) * 256 + dj];
        M2[h * 260 + dj] = rel_msg[(h * R_TYPES + r) * 256 + dj];
    }
    if (tid < 8) pri[tid] = rel_pri[tid * R_TYPES + r] * 0.25f;
    __syncthreads();
    int el = tid >> 3;
    int h  = tid & 7;
    const float4* A4 = (const float4*)&A2[h * 260];
    const float4* M4 = (const float4*)&M2[h * 260];
    float prih = pri[h];

#pragma unroll 2
    for (int it = 0; it < EPAD_ALIGN / 32; ++it) {
        int le = it * 32 + el;
        int s = sl[le];
        if (s < 0) continue;                     // padding sentinel
        int dn = dl[le];
        const uint4* kp = (const uint4*)(kbuf + (size_t)s  * DIM + h * 16);
        const uint4* qp = (const uint4*)(qbuf + (size_t)dn * DIM + h * 16);
        const uint4* vp = (const uint4*)(vbuf + (size_t)s  * DIM + h * 16);
        uint4 ka = kp[0], kb4 = kp[1];
        uint4 qa = qp[0], qb4 = qp[1];
        uint4 va = vp[0], vb4 = vp[1];
        float kk[16], qq[16], vv[16];
        bf2x(ka.x,  kk[0],  kk[1]);  bf2x(ka.y,  kk[2],  kk[3]);
        bf2x(ka.z,  kk[4],  kk[5]);  bf2x(ka.w,  kk[6],  kk[7]);
        bf2x(kb4.x, kk[8],  kk[9]);  bf2x(kb4.y, kk[10], kk[11]);
        bf2x(kb4.z, kk[12], kk[13]); bf2x(kb4.w, kk[14], kk[15]);
        bf2x(qa.x,  qq[0],  qq[1]);  bf2x(qa.y,  qq[2],  qq[3]);
        bf2x(qa.z,  qq[4],  qq[5]);  bf2x(qa.w,  qq[6],  qq[7]);
        bf2x(qb4.x, qq[8],  qq[9]);  bf2x(qb4.y, qq[10], qq[11]);
        bf2x(qb4.z, qq[12], qq[13]); bf2x(qb4.w, qq[14], qq[15]);
        bf2x(va.x,  vv[0],  vv[1]);  bf2x(va.y,  vv[2],  vv[3]);
        bf2x(va.z,  vv[4],  vv[5]);  bf2x(va.w,  vv[6],  vv[7]);
        bf2x(vb4.x, vv[8],  vv[9]);  bf2x(vb4.y, vv[10], vv[11]);
        bf2x(vb4.z, vv[12], vv[13]); bf2x(vb4.w, vv[14], vv[15]);

        // QK^T: accj[j] = sum_d k_d A[d][j]; a = accj . q
        float accj[16];
#pragma unroll
        for (int j = 0; j < 16; ++j) accj[j] = 0.f;
#pragma unroll
        for (int d = 0; d < 16; ++d) {
            float kd = kk[d];
#pragma unroll
            for (int jj = 0; jj < 4; ++jj) {
                float4 a4 = A4[d * 4 + jj];
                accj[jj * 4 + 0] = fmaf(kd, a4.x, accj[jj * 4 + 0]);
                accj[jj * 4 + 1] = fmaf(kd, a4.y, accj[jj * 4 + 1]);
                accj[jj * 4 + 2] = fmaf(kd, a4.z, accj[jj * 4 + 2]);
                accj[jj * 4 + 3] = fmaf(kd, a4.w, accj[jj * 4 + 3]);
            }
        }
        float a = 0.f;
#pragma unroll
        for (int j = 0; j < 16; ++j) a = fmaf(accj[j], qq[j], a);
        float ex = __expf(a * prih - SM_SHIFT);

        // message: m[j] = ex * sum_d v_d M[d][j]
        float mj[16];
#pragma unroll
        for (int j = 0; j < 16; ++j) mj[j] = 0.f;
#pragma unroll
        for (int d = 0; d < 16; ++d) {
            float vd = vv[d];
#pragma unroll
            for (int jj = 0; jj < 4; ++jj) {
                float4 m4 = M4[d * 4 + jj];
                mj[jj * 4 + 0] = fmaf(vd, m4.x, mj[jj * 4 + 0]);
                mj[jj * 4 + 1] = fmaf(vd, m4.y, mj[jj * 4 + 1]);
                mj[jj * 4 + 2] = fmaf(vd, m4.z, mj[jj * 4 + 2]);
                mj[jj * 4 + 3] = fmaf(vd, m4.w, mj[jj * 4 + 3]);
            }
        }
        int dp = pl[le];
        ex_out[(size_t)dp * 8 + h] = ex;
        uint4 o0, o1;
        o0.x = pk(ex * mj[0],  ex * mj[1]);  o0.y = pk(ex * mj[2],  ex * mj[3]);
        o0.z = pk(ex * mj[4],  ex * mj[5]);  o0.w = pk(ex * mj[6],  ex * mj[7]);
        o1.x = pk(ex * mj[8],  ex * mj[9]);  o1.y = pk(ex * mj[10], ex * mj[11]);
        o1.z = pk(ex * mj[12], ex * mj[13]); o1.w = pk(ex * mj[14], ex * mj[15]);
        uint4* op = (uint4*)(m_out + (size_t)dp * DIM + h * 16);
        op[0] = o0; op[1] = o1;
    }
}

// ======================= K3: fused aggregate + Wa + gate + LayerNorm ==========

__global__ __launch_bounds__(256) void k_final2(
    const float* __restrict__ x, const int* __restrict__ nlist,
    const int* __restrict__ tile_type, const int* __restrict__ ntiles_g,
    const bf16_t* __restrict__ m_out, const float* __restrict__ ex_out,
    const int* __restrict__ doffD, const int* __restrict__ degD,
    const float* __restrict__ Wa, const float* __restrict__ skip,
    const float* __restrict__ gamma, const float* __restrict__ beta,
    float* __restrict__ out) {
    __shared__ float hs[BN][DIM];
    __shared__ float ys[BN][DIM];
    __shared__ int sids[BN];
    __shared__ float mred[BN], ired[BN];
    int b = blockIdx.x;
    if (b >= *ntiles_g) return;
    int tid = threadIdx.x;
    if (tid < BN) sids[tid] = nlist[b * BN + tid];
    __syncthreads();
    // ---- aggregate: 16 nodes x 16 threads; thread covers elems 8d..8d+7 ----
    {
        int row = tid >> 4, d = tid & 15;
        int nid = sids[row];
        float a0=0.f,a1=0.f,a2=0.f,a3=0.f,a4=0.f,a5=0.f,a6=0.f,a7=0.f;
        float den = 0.f;
        if (nid >= 0) {
            int off = doffD[nid];
            int dg  = degD[nid];
            int hh = d >> 1;
#pragma unroll 4
            for (int j = 0; j < dg; ++j) {
                den += ex_out[(size_t)(off + j) * 8 + hh];
                uint4 mv = *(const uint4*)(m_out + (size_t)(off + j) * DIM + d * 8);
                float u, w;
                bf2x(mv.x, u, w); a0 += u; a1 += w;
                bf2x(mv.y, u, w); a2 += u; a3 += w;
                bf2x(mv.z, u, w); a4 += u; a5 += w;
                bf2x(mv.w, u, w); a6 += u; a7 += w;
            }
        }
        float inv = 1.f / fmaxf(den, 1e-9f);
        float* hp = &hs[row][d * 8];
        hp[0] = a0 * inv; hp[1] = a1 * inv; hp[2] = a2 * inv; hp[3] = a3 * inv;
        hp[4] = a4 * inv; hp[5] = a5 * inv; hp[6] = a6 * inv; hp[7] = a7 * inv;
    }
    __syncthreads();
    // ---- Wa matvec + gate + residual ----
    int t = tile_type[b];
    int half = tid >> 7, col = tid & 127;
    const float* W = Wa + (size_t)t * DIM * DIM;
    float acc[8];
#pragma unroll
    for (int n = 0; n < 8; ++n) acc[n] = 0.f;
#pragma unroll 4
    for (int d = 0; d < DIM; ++d) {
        float w = W[d * DIM + col];
#pragma unroll
        for (int n = 0; n < 8; ++n) acc[n] = fmaf(hs[half * 8 + n][d], w, acc[n]);
    }
    float gte = 1.f / (1.f + __expf(-skip[t]));
#pragma unroll
    for (int n = 0; n < 8; ++n) {
        int row = half * 8 + n;
        int nid = sids[row];
        float xv = (nid >= 0) ? x[(size_t)nid * DIM + col] : 0.f;
        ys[row][col] = xv * (2.f - gte) + acc[n] * gte;   // x + h*g + x*(1-g)
    }
    __syncthreads();
    // ---- LayerNorm ----
    int ng = tid >> 4, l16 = tid & 15;
    float s = 0.f, s2 = 0.f;
#pragma unroll
    for (int k2 = 0; k2 < 8; ++k2) {
        float yv = ys[ng][l16 + 16 * k2];
        s += yv; s2 += yv * yv;
    }
#pragma unroll
    for (int m = 1; m < 16; m <<= 1) {
        s  += __shfl_xor(s, m, 64);
        s2 += __shfl_xor(s2, m, 64);
    }
    if (l16 == 0) {
        float mu = s * (1.f / DIM);
        float var = s2 * (1.f / DIM) - mu * mu;
        mred[ng] = mu;
        ired[ng] = rsqrtf(var + 1e-5f);
    }
    __syncthreads();
    float gm = gamma[col], bt = beta[col];
#pragma unroll
    for (int n = 0; n < 8; ++n) {
        int row = half * 8 + n;
        int nid = sids[row];
        if (nid >= 0)
            out[(size_t)nid * DIM + col] = (ys[row][col] - mred[row]) * ired[row] * gm + bt;
    }
}

// ======================= launcher =======================

extern "C" void kernel_launch(void* const* d_in, const int* in_sizes, int n_in,
                              void* d_out, int out_size, void* d_ws, size_t ws_size,
                              hipStream_t stream) {
    const float* x       = (const float*)d_in[0];
    const int*   src     = (const int*)d_in[1];
    const int*   dst     = (const int*)d_in[2];
    const int*   ntype   = (const int*)d_in[3];
    const int*   etype   = (const int*)d_in[4];
    const float* Wk      = (const float*)d_in[5];
    const float* Wq      = (const float*)d_in[6];
    const float* Wv      = (const float*)d_in[7];
    const float* Wa      = (const float*)d_in[8];
    const float* rel_pri = (const float*)d_in[9];
    const float* rel_att = (const float*)d_in[10];
    const float* rel_msg = (const float*)d_in[11];
    const float* skip    = (const float*)d_in[12];
    const float* gamma   = (const float*)d_in[13];
    const float* beta    = (const float*)d_in[14];
    float* out = (float*)d_out;

    const int N = N_NODES, E = N_EDGES;

    // workspace layout (deg6, degD, tcnt contiguous so one memset covers them)
    char* ws = (char*)d_ws;
    float* ex_out = (float*)ws;                         // E*8 f32 (12.8 MB)
    int* deg6    = (int*)(ex_out + (size_t)E * H_HEADS);// NKEYS
    int* degD    = deg6 + NKEYS;                        // N
    int* tcnt    = degD + N;                            // T_TYPES
    int* offs6   = tcnt + T_TYPES;                      // NKEYS
    int* partial6 = offs6 + NKEYS;                      // NBLK_K
    int* doffD   = partial6 + NBLK_K;                   // N
    int* partialD = doffD + N;                          // NBLK_N
    int* cursor6 = partialD + NBLK_N;                   // NKEYS
    int* cursorD = cursor6 + NKEYS;                     // N
    int* rb_pad  = cursorD + N;                         // R_TYPES+1
    int* rstart  = rb_pad + R_TYPES + 1;                // R_TYPES
    int* dpos    = rstart + R_TYPES;                    // EPAD_MAX
    int* esrc_s  = dpos + EPAD_MAX;                     // EPAD_MAX
    int* edst_s  = esrc_s + EPAD_MAX;                   // EPAD_MAX
    int* pbase   = edst_s + EPAD_MAX;                   // T_TYPES
    int* ntiles  = pbase + T_TYPES;                     // 1
    int* tile_type = ntiles + 1;                        // MAX_TILES
    int* nlist   = tile_type + MAX_TILES;               // MAX_TILES*BN
    int* wpos    = nlist + (size_t)MAX_TILES * BN;      // N
    bf16_t* kb   = (bf16_t*)(wpos + N);                 // N*DIM bf16
    bf16_t* qb   = kb + (size_t)N * DIM;                // N*DIM
    bf16_t* vb   = qb + (size_t)N * DIM;                // N*DIM
    bf16_t* m_out = vb + (size_t)N * DIM;               // E*DIM bf16 (102.4 MB)

    const int nbE = (E + 255) / 256;

    // counts (one memset covers deg6+degD+tcnt; combo also builds wpos)
    hipMemsetAsync(deg6, 0, (size_t)(NKEYS + N + T_TYPES) * sizeof(int), stream);
    k_count_combo<<<nbE, 256, 0, stream>>>(
        src, dst, etype, ntype, deg6, degD, tcnt, wpos, E, N);

    // scans (both block-scans in one grid)
    k_scanAB<<<NBLK_K + NBLK_N, 256, 0, stream>>>(
        deg6, offs6, partial6, degD, doffD, partialD);
    k_scan_small<<<1, 256, 0, stream>>>(
        partial6, partialD, offs6, tcnt, rb_pad, rstart, pbase, ntiles,
        tile_type, nlist, esrc_s, E);

    // cursors (cursor6 + doffD finalize + cursorD)
    k_cursor_combo<<<NBLK_K, 256, 0, stream>>>(
        offs6, partial6, rb_pad, rstart, cursor6, doffD, partialD, cursorD,
        NKEYS, N);

    // scatters (edges + node tiles)
    k_scatter_combo<<<nbE, 256, 0, stream>>>(
        src, dst, etype, ntype, cursor6, cursorD, esrc_s, edst_s, dpos,
        wpos, pbase, nlist, E, N);

    // projections (tiled per-type GEMM, bf16 outputs)
    k_kqv_gemm4<<<MAX_TILES, 192, 0, stream>>>(
        x, nlist, tile_type, ntiles, Wk, Wq, Wv, kb, qb, vb);

    // fused edge kernel: QK^T, exp, M.v -> dst-major ex/m (128 edges/block)
    k_edge_m4<<<EPAD_MAX / EPAD_ALIGN, 256, 0, stream>>>(
        kb, qb, vb, esrc_s, edst_s, rb_pad, dpos,
        rel_att, rel_msg, rel_pri, ex_out, m_out);

    // fused aggregate + output projection + gate + residual + LayerNorm
    k_final2<<<MAX_TILES, 256, 0, stream>>>(
        x, nlist, tile_type, ntiles, m_out, ex_out, doffD, degD,
        Wa, skip, gamma, beta, out);
}

// Round 20
// 311.257 us; speedup vs baseline: 1.2748x; 1.0601x over previous
//
#include <hip/hip_runtime.h>
#include <math.h>

#define N_NODES 50000
#define N_EDGES 400000
#define H_HEADS 8
#define D_HEAD 16
#define R_TYPES 6
#define T_TYPES 4
#define DIM 128
#define BN 16                                      // nodes per GEMM tile
#define MAX_TILES ((N_NODES + BN - 1) / BN + T_TYPES)
#define NKEYS (N_NODES * R_TYPES)                  // 300000 (r,src) buckets, r-major
#define NBLK_K ((NKEYS + 255) / 256)               // 1172
#define NBLK_N ((N_NODES + 255) / 256)             // 196
#define EPAD_ALIGN 256                             // r-segment alignment (= edges/block)
#define EPAD_MAX (N_EDGES + R_TYPES * EPAD_ALIGN)  // 401536
#define SM_SHIFT 8.0f                              // constant softmax shift

typedef unsigned short bf16_t;

__device__ __forceinline__ float bf2f(bf16_t u) {
    unsigned int v = ((unsigned int)u) << 16;
    return __int_as_float((int)v);
}
__device__ __forceinline__ bf16_t f2bf(float f) {
    unsigned int u = (unsigned int)__float_as_int(f);
    unsigned int lsb = (u >> 16) & 1u;
    u += 0x7fffu + lsb;                            // round-to-nearest-even
    return (bf16_t)(u >> 16);
}
__device__ __forceinline__ void bf2x(unsigned int u, float& a, float& b) {
    a = bf2f((bf16_t)(u & 0xffffu));
    b = bf2f((bf16_t)(u >> 16));
}
__device__ __forceinline__ unsigned int pk(float a, float b) {
    return (unsigned int)f2bf(a) | ((unsigned int)f2bf(b) << 16);
}

// ======================= scans =======================
// fused block-scan: blocks [0,NBLK_K) scan deg6, blocks [NBLK_K,+NBLK_N) scan degD

__global__ void k_scanAB(const int* __restrict__ cnt6, int* __restrict__ offs6,
                         int* __restrict__ partial6,
                         const int* __restrict__ cntD, int* __restrict__ offsD,
                         int* __restrict__ partialD) {
    __shared__ int tmp[256];
    int blk = blockIdx.x;
    const int* cnt; int* offs; int* partial; int n; int bb;
    if (blk < NBLK_K) { cnt = cnt6; offs = offs6; partial = partial6; n = NKEYS; bb = blk; }
    else { cnt = cntD; offs = offsD; partial = partialD; n = N_NODES; bb = blk - NBLK_K; }
    int tid = threadIdx.x;
    int i = bb * 256 + tid;
    int v = (i < n) ? cnt[i] : 0;
    tmp[tid] = v;
    __syncthreads();
    for (int o = 1; o < 256; o <<= 1) {
        int t = (tid >= o) ? tmp[tid - o] : 0;
        __syncthreads();
        tmp[tid] += t;
        __syncthreads();
    }
    if (i < n) offs[i] = tmp[tid] - v;           // exclusive within block
    if (tid == 255) partial[bb] = tmp[255];
}

__device__ void dev_rscan(int* a, int total, int* tmp, int* carry_s) {
    int tid = threadIdx.x;
    if (tid == 0) *carry_s = 0;
    __syncthreads();
    for (int base = 0; base < total; base += 256) {
        int i = base + tid;
        int v = (i < total) ? a[i] : 0;
        tmp[tid] = v;
        __syncthreads();
        for (int o = 1; o < 256; o <<= 1) {
            int t = (tid >= o) ? tmp[tid - o] : 0;
            __syncthreads();
            tmp[tid] += t;
            __syncthreads();
        }
        int carry = *carry_s;
        if (i < total) a[i] = carry + tmp[tid] - v;   // exclusive
        __syncthreads();
        if (tid == 255) *carry_s = carry + tmp[255];
        __syncthreads();
    }
}

// ======================= fused counts: edge degrees + node-type histogram =====

__global__ void k_count_combo(const int* __restrict__ src, const int* __restrict__ dst,
                              const int* __restrict__ etype, const int* __restrict__ ntype,
                              int* __restrict__ deg6, int* __restrict__ degD,
                              int* __restrict__ tcnt, int* __restrict__ wpos,
                              int nE, int nN) {
    __shared__ int hist[T_TYPES];
    __shared__ int base[T_TYPES];
    int tid = threadIdx.x;
    int i = blockIdx.x * 256 + tid;
    if (tid < T_TYPES) hist[tid] = 0;
    __syncthreads();
    if (i < nE) {
        atomicAdd(&deg6[etype[i] * N_NODES + src[i]], 1);
        atomicAdd(&degD[dst[i]], 1);
    }
    int t = 0, rank = 0;
    if (i < nN) {
        t = ntype[i];
        rank = atomicAdd(&hist[t], 1);
    }
    __syncthreads();
    if (tid < T_TYPES)
        base[tid] = (hist[tid] > 0) ? atomicAdd(&tcnt[tid], hist[tid]) : 0;
    __syncthreads();
    if (i < nN) wpos[i] = base[t] + rank;
}

// ======================= single-block: both partial scans + serial setup ======

__global__ void k_scan_small(int* __restrict__ partial6, int* __restrict__ partialD,
                             const int* __restrict__ offs6, const int* __restrict__ tcnt,
                             int* __restrict__ rb_pad, int* __restrict__ rstart,
                             int* __restrict__ pbase, int* __restrict__ ntiles_g,
                             int* __restrict__ tile_type, int* __restrict__ nlist,
                             int* __restrict__ esrc_s, int nE) {
    __shared__ int tmp[256];
    __shared__ int carry_s;
    __shared__ int rbp[R_TYPES + 1], len[R_TYPES];
    __shared__ int off_t[T_TYPES + 1];
    int tid = threadIdx.x;
    dev_rscan(partial6, NBLK_K, tmp, &carry_s);
    __syncthreads();
    dev_rscan(partialD, NBLK_N, tmp, &carry_s);
    __syncthreads();
    if (tid == 0) {
        int o = 0;
        int st = offs6[0] + partial6[0];
        for (int r = 0; r < R_TYPES; ++r) {
            int idx1 = (r + 1) * N_NODES;
            int en = (r < R_TYPES - 1) ? (offs6[idx1] + partial6[idx1 >> 8]) : nE;
            rstart[r] = st;
            len[r] = en - st;
            rbp[r] = o; rb_pad[r] = o;
            o += (en - st + EPAD_ALIGN - 1) & ~(EPAD_ALIGN - 1);
            st = en;
        }
        rbp[R_TYPES] = o; rb_pad[R_TYPES] = o;
        int o2 = 0;
        for (int t = 0; t < T_TYPES; ++t) {
            off_t[t] = o2;
            pbase[t] = o2 * BN;
            o2 += (tcnt[t] + BN - 1) / BN;
        }
        off_t[T_TYPES] = o2;
        *ntiles_g = o2;
    }
    __syncthreads();
    // esrc sentinels: per-r pad gaps + tail
    for (int r = 0; r < R_TYPES; ++r)
        for (int i = rbp[r] + len[r] + tid; i < rbp[r + 1]; i += 256) esrc_s[i] = -1;
    for (int i = rbp[R_TYPES] + tid; i < EPAD_MAX; i += 256) esrc_s[i] = -1;
    // tile_type fill
    int total = off_t[T_TYPES];
    for (int i = tid; i < total; i += 256) {
        int t = 0;
        while (t < T_TYPES - 1 && i >= off_t[t + 1]) ++t;
        tile_type[i] = t;
    }
    // nlist pad sentinels
    for (int t = 0; t < T_TYPES; ++t) {
        int b0 = off_t[t] * BN + tcnt[t];
        int b1 = off_t[t + 1] * BN;
        for (int i = b0 + tid; i < b1; i += 256) nlist[i] = -1;
    }
}

// ======================= fused cursor init (cursor6 + doffD/cursorD) ==========

__global__ void k_cursor_combo(const int* __restrict__ offs6, const int* __restrict__ partial6,
                               const int* __restrict__ rb_pad, const int* __restrict__ rstart,
                               int* __restrict__ cursor6,
                               int* __restrict__ doffD, const int* __restrict__ partialD,
                               int* __restrict__ cursorD, int nK, int nN) {
    int i = blockIdx.x * 256 + threadIdx.x;
    if (i < nK) {
        int r = i / N_NODES;
        int v = offs6[i] + partial6[i >> 8];
        cursor6[i] = rb_pad[r] + (v - rstart[r]);
    }
    if (i < nN) {
        int v = doffD[i] + partialD[i >> 8];
        doffD[i] = v;
        cursorD[i] = v;
    }
}

// ======================= fused scatters (edges + node tiles) ==================

__global__ void k_scatter_combo(const int* __restrict__ src, const int* __restrict__ dst,
                                const int* __restrict__ etype, const int* __restrict__ ntype,
                                int* __restrict__ cursor6,
                                int* __restrict__ esrc_s, int* __restrict__ edst_s,
                                const int* __restrict__ wpos, const int* __restrict__ pbase,
                                int* __restrict__ nlist, int nE, int nN) {
    int i = blockIdx.x * 256 + threadIdx.x;
    if (i < nE) {
        int dn = dst[i];
        int key = etype[i] * N_NODES + src[i];
        int pos = atomicAdd(&cursor6[key], 1);
        esrc_s[pos] = src[i];
        edst_s[pos] = dn;
    }
    if (i < nN) nlist[pbase[ntype[i]] + wpos[i]] = i;
}

// ======================= K1: tiled typed-linear k,q,v (bf16 out) ==========

__global__ __launch_bounds__(192) void k_kqv_gemm4(
    const float* __restrict__ x, const int* __restrict__ nlist,
    const int* __restrict__ tile_type, const int* __restrict__ ntiles_g,
    const float* __restrict__ Wk, const float* __restrict__ Wq,
    const float* __restrict__ Wv,
    bf16_t* __restrict__ kb, bf16_t* __restrict__ qb, bf16_t* __restrict__ vb) {
    __shared__ float xs[BN][DIM];   // 8 KB
    __shared__ int sids[BN];
    int b = blockIdx.x;
    if (b >= *ntiles_g) return;
    int tid = threadIdx.x;
    if (tid < BN) sids[tid] = nlist[b * BN + tid];
    __syncthreads();
    for (int idx = tid; idx < BN * (DIM / 4); idx += 192) {
        int row = idx >> 5;
        int q4 = idx & 31;
        int nid = sids[row];
        float4 v4 = make_float4(0.f, 0.f, 0.f, 0.f);
        if (nid >= 0) v4 = *(const float4*)(x + (size_t)nid * DIM + q4 * 4);
        *(float4*)(&xs[row][q4 * 4]) = v4;
    }
    __syncthreads();
    int lt = tid / 96;
    int wi = tid % 96;
    int mat = wi >> 5;
    int colq = wi & 31;
    int t = tile_type[b];
    const float* W = (mat == 0 ? Wk : (mat == 1 ? Wq : Wv))
                     + (size_t)t * DIM * DIM + colq * 4;
    float acc[8][4];
#pragma unroll
    for (int n = 0; n < 8; ++n) {
        acc[n][0] = 0.f; acc[n][1] = 0.f; acc[n][2] = 0.f; acc[n][3] = 0.f;
    }
    const float* xbase = &xs[lt * 8][0];
    for (int dq = 0; dq < 32; ++dq) {
        float4 w0 = *(const float4*)(W + (size_t)(dq * 4 + 0) * DIM);
        float4 w1 = *(const float4*)(W + (size_t)(dq * 4 + 1) * DIM);
        float4 w2 = *(const float4*)(W + (size_t)(dq * 4 + 2) * DIM);
        float4 w3 = *(const float4*)(W + (size_t)(dq * 4 + 3) * DIM);
#pragma unroll
        for (int n = 0; n < 8; ++n) {
            float4 xv = *(const float4*)(xbase + n * DIM + dq * 4);
            acc[n][0] = fmaf(xv.x, w0.x, acc[n][0]);
            acc[n][0] = fmaf(xv.y, w1.x, acc[n][0]);
            acc[n][0] = fmaf(xv.z, w2.x, acc[n][0]);
            acc[n][0] = fmaf(xv.w, w3.x, acc[n][0]);
            acc[n][1] = fmaf(xv.x, w0.y, acc[n][1]);
            acc[n][1] = fmaf(xv.y, w1.y, acc[n][1]);
            acc[n][1] = fmaf(xv.z, w2.y, acc[n][1]);
            acc[n][1] = fmaf(xv.w, w3.y, acc[n][1]);
            acc[n][2] = fmaf(xv.x, w0.z, acc[n][2]);
            acc[n][2] = fmaf(xv.y, w1.z, acc[n][2]);
            acc[n][2] = fmaf(xv.z, w2.z, acc[n][2]);
            acc[n][2] = fmaf(xv.w, w3.z, acc[n][2]);
            acc[n][3] = fmaf(xv.x, w0.w, acc[n][3]);
            acc[n][3] = fmaf(xv.y, w1.w, acc[n][3]);
            acc[n][3] = fmaf(xv.z, w2.w, acc[n][3]);
            acc[n][3] = fmaf(xv.w, w3.w, acc[n][3]);
        }
    }
    bf16_t* ob = (mat == 0 ? kb : (mat == 1 ? qb : vb));
#pragma unroll
    for (int n = 0; n < 8; ++n) {
        int nid = sids[lt * 8 + n];
        if (nid >= 0) {
            ushort4 o4;
            o4.x = f2bf(acc[n][0]); o4.y = f2bf(acc[n][1]);
            o4.z = f2bf(acc[n][2]); o4.w = f2bf(acc[n][3]);
            *(ushort4*)(ob + (size_t)nid * DIM + colq * 4) = o4;
        }
    }
}

// ======================= K2: fused edge kernel (256 edges/block, v5) ==========
// A/M staging amortized over 256 edges; indices LDS-staged; dpos computed
// in-kernel (h==0 lane atomicAdd early, shfl to the edge's 8 lanes).

__global__ __launch_bounds__(256) void k_edge_m5(
    const bf16_t* __restrict__ kbuf, const bf16_t* __restrict__ qbuf,
    const bf16_t* __restrict__ vbuf,
    const int* __restrict__ esrc_s, const int* __restrict__ edst_s,
    const int* __restrict__ rb_pad, int* __restrict__ cursorD,
    const float* __restrict__ rel_att, const float* __restrict__ rel_msg,
    const float* __restrict__ rel_pri,
    float* __restrict__ ex_out, bf16_t* __restrict__ m_out) {
    __shared__ float A2[8 * 260];   // 8.3 KB
    __shared__ float M2[8 * 260];   // 8.3 KB
    __shared__ float pri[8];
    __shared__ int sl[EPAD_ALIGN], dl[EPAD_ALIGN];  // 2 KB
    __shared__ int r_s;
    int b = blockIdx.x;
    int e0 = b * EPAD_ALIGN;
    int tid = threadIdx.x;
    if (tid == 0) {
        int r = 0;
#pragma unroll
        for (int q = 1; q < R_TYPES; ++q) if (e0 >= rb_pad[q]) r = q;
        r_s = r;
    }
    sl[tid] = esrc_s[e0 + tid];
    dl[tid] = edst_s[e0 + tid];
    __syncthreads();
    int r = r_s;
    for (int idx = tid; idx < 2048; idx += 256) {
        int h = idx >> 8, dj = idx & 255;
        A2[h * 260 + dj] = rel_att[(h * R_TYPES + r) * 256 + dj];
        M2[h * 260 + dj] = rel_msg[(h * R_TYPES + r) * 256 + dj];
    }
    if (tid < 8) pri[tid] = rel_pri[tid * R_TYPES + r] * 0.25f;
    __syncthreads();
    int el = tid >> 3;
    int h  = tid & 7;
    int lane = tid & 63;
    const float4* A4 = (const float4*)&A2[h * 260];
    const float4* M4 = (const float4*)&M2[h * 260];
    float prih = pri[h];

#pragma unroll 2
    for (int it = 0; it < EPAD_ALIGN / 32; ++it) {
        int le = it * 32 + el;
        int s = sl[le];
        if (s < 0) continue;                     // padding sentinel
        int dn = dl[le];
        // dst-major write slot: one atomic per edge, issued early, shared by shfl
        int dp = 0;
        if (h == 0) dp = atomicAdd(&cursorD[dn], 1);
        const uint4* kp = (const uint4*)(kbuf + (size_t)s  * DIM + h * 16);
        const uint4* qp = (const uint4*)(qbuf + (size_t)dn * DIM + h * 16);
        const uint4* vp = (const uint4*)(vbuf + (size_t)s  * DIM + h * 16);
        uint4 ka = kp[0], kb4 = kp[1];
        uint4 qa = qp[0], qb4 = qp[1];
        uint4 va = vp[0], vb4 = vp[1];
        float kk[16], qq[16], vv[16];
        bf2x(ka.x,  kk[0],  kk[1]);  bf2x(ka.y,  kk[2],  kk[3]);
        bf2x(ka.z,  kk[4],  kk[5]);  bf2x(ka.w,  kk[6],  kk[7]);
        bf2x(kb4.x, kk[8],  kk[9]);  bf2x(kb4.y, kk[10], kk[11]);
        bf2x(kb4.z, kk[12], kk[13]); bf2x(kb4.w, kk[14], kk[15]);
        bf2x(qa.x,  qq[0],  qq[1]);  bf2x(qa.y,  qq[2],  qq[3]);
        bf2x(qa.z,  qq[4],  qq[5]);  bf2x(qa.w,  qq[6],  qq[7]);
        bf2x(qb4.x, qq[8],  qq[9]);  bf2x(qb4.y, qq[10], qq[11]);
        bf2x(qb4.z, qq[12], qq[13]); bf2x(qb4.w, qq[14], qq[15]);
        bf2x(va.x,  vv[0],  vv[1]);  bf2x(va.y,  vv[2],  vv[3]);
        bf2x(va.z,  vv[4],  vv[5]);  bf2x(va.w,  vv[6],  vv[7]);
        bf2x(vb4.x, vv[8],  vv[9]);  bf2x(vb4.y, vv[10], vv[11]);
        bf2x(vb4.z, vv[12], vv[13]); bf2x(vb4.w, vv[14], vv[15]);

        // QK^T: accj[j] = sum_d k_d A[d][j]; a = accj . q
        float accj[16];
#pragma unroll
        for (int j = 0; j < 16; ++j) accj[j] = 0.f;
#pragma unroll
        for (int d = 0; d < 16; ++d) {
            float kd = kk[d];
#pragma unroll
            for (int jj = 0; jj < 4; ++jj) {
                float4 a4 = A4[d * 4 + jj];
                accj[jj * 4 + 0] = fmaf(kd, a4.x, accj[jj * 4 + 0]);
                accj[jj * 4 + 1] = fmaf(kd, a4.y, accj[jj * 4 + 1]);
                accj[jj * 4 + 2] = fmaf(kd, a4.z, accj[jj * 4 + 2]);
                accj[jj * 4 + 3] = fmaf(kd, a4.w, accj[jj * 4 + 3]);
            }
        }
        float a = 0.f;
#pragma unroll
        for (int j = 0; j < 16; ++j) a = fmaf(accj[j], qq[j], a);
        float ex = __expf(a * prih - SM_SHIFT);

        // message: m[j] = ex * sum_d v_d M[d][j]
        float mj[16];
#pragma unroll
        for (int j = 0; j < 16; ++j) mj[j] = 0.f;
#pragma unroll
        for (int d = 0; d < 16; ++d) {
            float vd = vv[d];
#pragma unroll
            for (int jj = 0; jj < 4; ++jj) {
                float4 m4 = M4[d * 4 + jj];
                mj[jj * 4 + 0] = fmaf(vd, m4.x, mj[jj * 4 + 0]);
                mj[jj * 4 + 1] = fmaf(vd, m4.y, mj[jj * 4 + 1]);
                mj[jj * 4 + 2] = fmaf(vd, m4.z, mj[jj * 4 + 2]);
                mj[jj * 4 + 3] = fmaf(vd, m4.w, mj[jj * 4 + 3]);
            }
        }
        dp = __shfl(dp, lane & ~7, 64);          // broadcast from h==0 lane
        ex_out[(size_t)dp * 8 + h] = ex;
        uint4 o0, o1;
        o0.x = pk(ex * mj[0],  ex * mj[1]);  o0.y = pk(ex * mj[2],  ex * mj[3]);
        o0.z = pk(ex * mj[4],  ex * mj[5]);  o0.w = pk(ex * mj[6],  ex * mj[7]);
        o1.x = pk(ex * mj[8],  ex * mj[9]);  o1.y = pk(ex * mj[10], ex * mj[11]);
        o1.z = pk(ex * mj[12], ex * mj[13]); o1.w = pk(ex * mj[14], ex * mj[15]);
        uint4* op = (uint4*)(m_out + (size_t)dp * DIM + h * 16);
        op[0] = o0; op[1] = o1;
    }
}

// ======================= K3: fused aggregate + Wa + gate + LayerNorm ==========

__global__ __launch_bounds__(256) void k_final2(
    const float* __restrict__ x, const int* __restrict__ nlist,
    const int* __restrict__ tile_type, const int* __restrict__ ntiles_g,
    const bf16_t* __restrict__ m_out, const float* __restrict__ ex_out,
    const int* __restrict__ doffD, const int* __restrict__ degD,
    const float* __restrict__ Wa, const float* __restrict__ skip,
    const float* __restrict__ gamma, const float* __restrict__ beta,
    float* __restrict__ out) {
    __shared__ float hs[BN][DIM];
    __shared__ float ys[BN][DIM];
    __shared__ int sids[BN];
    __shared__ float mred[BN], ired[BN];
    int b = blockIdx.x;
    if (b >= *ntiles_g) return;
    int tid = threadIdx.x;
    if (tid < BN) sids[tid] = nlist[b * BN + tid];
    __syncthreads();
    // ---- aggregate: 16 nodes x 16 threads; thread covers elems 8d..8d+7 ----
    {
        int row = tid >> 4, d = tid & 15;
        int nid = sids[row];
        float a0=0.f,a1=0.f,a2=0.f,a3=0.f,a4=0.f,a5=0.f,a6=0.f,a7=0.f;
        float den = 0.f;
        if (nid >= 0) {
            int off = doffD[nid];
            int dg  = degD[nid];
            int hh = d >> 1;
#pragma unroll 4
            for (int j = 0; j < dg; ++j) {
                den += ex_out[(size_t)(off + j) * 8 + hh];
                uint4 mv = *(const uint4*)(m_out + (size_t)(off + j) * DIM + d * 8);
                float u, w;
                bf2x(mv.x, u, w); a0 += u; a1 += w;
                bf2x(mv.y, u, w); a2 += u; a3 += w;
                bf2x(mv.z, u, w); a4 += u; a5 += w;
                bf2x(mv.w, u, w); a6 += u; a7 += w;
            }
        }
        float inv = 1.f / fmaxf(den, 1e-9f);
        float* hp = &hs[row][d * 8];
        hp[0] = a0 * inv; hp[1] = a1 * inv; hp[2] = a2 * inv; hp[3] = a3 * inv;
        hp[4] = a4 * inv; hp[5] = a5 * inv; hp[6] = a6 * inv; hp[7] = a7 * inv;
    }
    __syncthreads();
    // ---- Wa matvec + gate + residual ----
    int t = tile_type[b];
    int half = tid >> 7, col = tid & 127;
    const float* W = Wa + (size_t)t * DIM * DIM;
    float acc[8];
#pragma unroll
    for (int n = 0; n < 8; ++n) acc[n] = 0.f;
#pragma unroll 4
    for (int d = 0; d < DIM; ++d) {
        float w = W[d * DIM + col];
#pragma unroll
        for (int n = 0; n < 8; ++n) acc[n] = fmaf(hs[half * 8 + n][d], w, acc[n]);
    }
    float gte = 1.f / (1.f + __expf(-skip[t]));
#pragma unroll
    for (int n = 0; n < 8; ++n) {
        int row = half * 8 + n;
        int nid = sids[row];
        float xv = (nid >= 0) ? x[(size_t)nid * DIM + col] : 0.f;
        ys[row][col] = xv * (2.f - gte) + acc[n] * gte;   // x + h*g + x*(1-g)
    }
    __syncthreads();
    // ---- LayerNorm ----
    int ng = tid >> 4, l16 = tid & 15;
    float s = 0.f, s2 = 0.f;
#pragma unroll
    for (int k2 = 0; k2 < 8; ++k2) {
        float yv = ys[ng][l16 + 16 * k2];
        s += yv; s2 += yv * yv;
    }
#pragma unroll
    for (int m = 1; m < 16; m <<= 1) {
        s  += __shfl_xor(s, m, 64);
        s2 += __shfl_xor(s2, m, 64);
    }
    if (l16 == 0) {
        float mu = s * (1.f / DIM);
        float var = s2 * (1.f / DIM) - mu * mu;
        mred[ng] = mu;
        ired[ng] = rsqrtf(var + 1e-5f);
    }
    __syncthreads();
    float gm = gamma[col], bt = beta[col];
#pragma unroll
    for (int n = 0; n < 8; ++n) {
        int row = half * 8 + n;
        int nid = sids[row];
        if (nid >= 0)
            out[(size_t)nid * DIM + col] = (ys[row][col] - mred[row]) * ired[row] * gm + bt;
    }
}

// ======================= launcher =======================

extern "C" void kernel_launch(void* const* d_in, const int* in_sizes, int n_in,
                              void* d_out, int out_size, void* d_ws, size_t ws_size,
                              hipStream_t stream) {
    const float* x       = (const float*)d_in[0];
    const int*   src     = (const int*)d_in[1];
    const int*   dst     = (const int*)d_in[2];
    const int*   ntype   = (const int*)d_in[3];
    const int*   etype   = (const int*)d_in[4];
    const float* Wk      = (const float*)d_in[5];
    const float* Wq      = (const float*)d_in[6];
    const float* Wv      = (const float*)d_in[7];
    const float* Wa      = (const float*)d_in[8];
    const float* rel_pri = (const float*)d_in[9];
    const float* rel_att = (const float*)d_in[10];
    const float* rel_msg = (const float*)d_in[11];
    const float* skip    = (const float*)d_in[12];
    const float* gamma   = (const float*)d_in[13];
    const float* beta    = (const float*)d_in[14];
    float* out = (float*)d_out;

    const int N = N_NODES, E = N_EDGES;

    // workspace layout (deg6, degD, tcnt contiguous so one memset covers them)
    char* ws = (char*)d_ws;
    float* ex_out = (float*)ws;                         // E*8 f32 (12.8 MB)
    int* deg6    = (int*)(ex_out + (size_t)E * H_HEADS);// NKEYS
    int* degD    = deg6 + NKEYS;                        // N
    int* tcnt    = degD + N;                            // T_TYPES
    int* offs6   = tcnt + T_TYPES;                      // NKEYS
    int* partial6 = offs6 + NKEYS;                      // NBLK_K
    int* doffD   = partial6 + NBLK_K;                   // N
    int* partialD = doffD + N;                          // NBLK_N
    int* cursor6 = partialD + NBLK_N;                   // NKEYS
    int* cursorD = cursor6 + NKEYS;                     // N
    int* rb_pad  = cursorD + N;                         // R_TYPES+1
    int* rstart  = rb_pad + R_TYPES + 1;                // R_TYPES
    int* esrc_s  = rstart + R_TYPES;                    // EPAD_MAX
    int* edst_s  = esrc_s + EPAD_MAX;                   // EPAD_MAX
    int* pbase   = edst_s + EPAD_MAX;                   // T_TYPES
    int* ntiles  = pbase + T_TYPES;                     // 1
    int* tile_type = ntiles + 1;                        // MAX_TILES
    int* nlist   = tile_type + MAX_TILES;               // MAX_TILES*BN
    int* wpos    = nlist + (size_t)MAX_TILES * BN;      // N
    bf16_t* kb   = (bf16_t*)(wpos + N);                 // N*DIM bf16
    bf16_t* qb   = kb + (size_t)N * DIM;                // N*DIM
    bf16_t* vb   = qb + (size_t)N * DIM;                // N*DIM
    bf16_t* m_out = vb + (size_t)N * DIM;               // E*DIM bf16 (102.4 MB)

    const int nbE = (E + 255) / 256;

    // counts (one memset covers deg6+degD+tcnt; combo also builds wpos)
    hipMemsetAsync(deg6, 0, (size_t)(NKEYS + N + T_TYPES) * sizeof(int), stream);
    k_count_combo<<<nbE, 256, 0, stream>>>(
        src, dst, etype, ntype, deg6, degD, tcnt, wpos, E, N);

    // scans (both block-scans in one grid)
    k_scanAB<<<NBLK_K + NBLK_N, 256, 0, stream>>>(
        deg6, offs6, partial6, degD, doffD, partialD);
    k_scan_small<<<1, 256, 0, stream>>>(
        partial6, partialD, offs6, tcnt, rb_pad, rstart, pbase, ntiles,
        tile_type, nlist, esrc_s, E);

    // cursors (cursor6 + doffD finalize + cursorD)
    k_cursor_combo<<<NBLK_K, 256, 0, stream>>>(
        offs6, partial6, rb_pad, rstart, cursor6, doffD, partialD, cursorD,
        NKEYS, N);

    // scatters (edges + node tiles)
    k_scatter_combo<<<nbE, 256, 0, stream>>>(
        src, dst, etype, ntype, cursor6, esrc_s, edst_s,
        wpos, pbase, nlist, E, N);

    // projections (tiled per-type GEMM, bf16 outputs)
    k_kqv_gemm4<<<MAX_TILES, 192, 0, stream>>>(
        x, nlist, tile_type, ntiles, Wk, Wq, Wv, kb, qb, vb);

    // fused edge kernel: QK^T, exp, M.v -> dst-major ex/m (256 edges/block)
    k_edge_m5<<<EPAD_MAX / EPAD_ALIGN, 256, 0, stream>>>(
        kb, qb, vb, esrc_s, edst_s, rb_pad, cursorD,
        rel_att, rel_msg, rel_pri, ex_out, m_out);

    // fused aggregate + output projection + gate + residual + LayerNorm
    k_final2<<<MAX_TILES, 256, 0, stream>>>(
        x, nlist, tile_type, ntiles, m_out, ex_out, doffD, degD,
        Wa, skip, gamma, beta, out);
}